// Round 5
// baseline (272.762 us; speedup 1.0000x reference)
//
#include <hip/hip_runtime.h>
#include <hip/hip_bf16.h>
#include <stdint.h>

#define DIM     1024
#define SEQ     2048
#define NTOK    4096
#define HEADS   8
#define DH      64
#define AINNER  512
#define FFI     4096
#define FUSED   8832
#define HCOLS   4608   // 512 attn-out cols + 4096 gated-ff cols

typedef __attribute__((ext_vector_type(8))) short short8;
typedef __attribute__((ext_vector_type(4))) short short4v;
typedef __attribute__((ext_vector_type(4))) float f32x4;

__device__ __forceinline__ short f2bf(float f) {
  union { float f; uint32_t u; } v; v.f = f;
  uint32_t r = v.u + 0x7fffu + ((v.u >> 16) & 1u);
  return (short)(r >> 16);
}
__device__ __forceinline__ float bf2f(short s) {
  union { uint32_t u; float f; } v; v.u = ((uint32_t)(uint16_t)s) << 16;
  return v.f;
}
__device__ __forceinline__ void g2l16(const void* g, void* l) {
  __builtin_amdgcn_global_load_lds((const __attribute__((address_space(1))) void*)g,
                                   (__attribute__((address_space(3))) void*)l, 16, 0, 0);
}

// ---------------- transpose + f32->bf16 convert -----------------------------
__global__ __launch_bounds__(256) void k_transpose_wf(const float* __restrict__ src,
                                                      short* __restrict__ dst) {
  __shared__ short tile[32][33];
  int c0 = blockIdx.x * 32;
  int r0 = blockIdx.y * 32;
  int tx = threadIdx.x & 31, ty = threadIdx.x >> 5;
#pragma unroll
  for (int i = 0; i < 32; i += 8)
    tile[ty + i][tx] = f2bf(src[(size_t)(r0 + ty + i) * FUSED + c0 + tx]);
  __syncthreads();
#pragma unroll
  for (int i = 0; i < 32; i += 8)
    dst[(size_t)(c0 + ty + i) * DIM + r0 + tx] = tile[tx][ty + i];
}

__global__ __launch_bounds__(256) void k_transpose_w2(const float* __restrict__ wao,
                                                      const float* __restrict__ wfo,
                                                      short* __restrict__ dst) {
  __shared__ short tile[32][33];
  int c0 = blockIdx.x * 32;
  int r0 = blockIdx.y * 32;
  int tx = threadIdx.x & 31, ty = threadIdx.x >> 5;
#pragma unroll
  for (int i = 0; i < 32; i += 8) {
    int r = r0 + ty + i;
    float v = (r < AINNER) ? wao[(size_t)r * DIM + c0 + tx]
                           : wfo[(size_t)(r - AINNER) * DIM + c0 + tx];
    tile[ty + i][tx] = f2bf(v);
  }
  __syncthreads();
#pragma unroll
  for (int i = 0; i < 32; i += 8)
    dst[(size_t)(c0 + ty + i) * HCOLS + r0 + tx] = tile[tx][ty + i];
}

// ---------------- layernorm -------------------------------------------------
__global__ __launch_bounds__(256) void k_ln(const float* __restrict__ x,
                                            const float* __restrict__ gamma,
                                            short* __restrict__ xn) {
  int row = blockIdx.x;
  int t = threadIdx.x;
  const float4* xr = (const float4*)(x + (size_t)row * DIM);
  float4 v = xr[t];
  float s = v.x + v.y + v.z + v.w;
  float s2 = v.x * v.x + v.y * v.y + v.z * v.z + v.w * v.w;
#pragma unroll
  for (int m = 1; m < 64; m <<= 1) { s += __shfl_xor(s, m); s2 += __shfl_xor(s2, m); }
  __shared__ float red[8];
  int w = t >> 6;
  if ((t & 63) == 0) { red[w] = s; red[4 + w] = s2; }
  __syncthreads();
  s = red[0] + red[1] + red[2] + red[3];
  s2 = red[4] + red[5] + red[6] + red[7];
  float mu = s * (1.f / DIM);
  float rs = rsqrtf(s2 * (1.f / DIM) - mu * mu + 1e-5f);
  const float4* g4 = (const float4*)gamma;
  float4 g = g4[t];
  short4v o;
  o.x = f2bf((v.x - mu) * rs * g.x);
  o.y = f2bf((v.y - mu) * rs * g.y);
  o.z = f2bf((v.z - mu) * rs * g.z);
  o.w = f2bf((v.w - mu) * rs * g.w);
  ((short4v*)(xn + (size_t)row * DIM))[t] = o;
}

// ---------------- B^T GEMM: 128x128 tile, 4 waves, 64x64 wave tile ----------
// 256 threads, BK=64, static 64KB LDS double-buffer, 2 blocks/CU.
// Per K-step/wave: 16 ds_read_b128, 32 MFMA (0.5 reads/MFMA).
// MODE 0: qkv+ffx split write; 1: H = silu(gate)*H (RMW); 2: f32 out
template <int MODE>
__global__ __launch_bounds__(256, 2) void gemm_p(const short* __restrict__ A, int lda,
                                                 const short* __restrict__ Bt, int ldb,
                                                 int K, void* __restrict__ out0,
                                                 void* __restrict__ out1,
                                                 void* __restrict__ out2,
                                                 void* __restrict__ out3) {
  __shared__ __align__(16) short As[2][128 * 64];
  __shared__ __align__(16) short Bs[2][128 * 64];
  int tid = threadIdx.x, l = tid & 63, w = tid >> 6;
  int gx = gridDim.x;
  int nwg = gx * gridDim.y;
  int hw = blockIdx.y * gx + blockIdx.x;
  int qq = nwg >> 3;                       // all grids divisible by 8
  int tile = (hw & 7) * qq + (hw >> 3);    // XCD-contiguous remap
  int bx = tile % gx, by = tile / gx;
  int mBase = by * 128, nBase = bx * 128;

  // staging: instr i covers rows i*32 + w*8 + (l>>3), chunk (l&7)^(l>>3)
  int srow = w * 8 + (l >> 3);
  int cs = (l & 7) ^ (l >> 3);
  const short* Ag = A + (size_t)(mBase + srow) * lda + cs * 8;
  const short* Bg = Bt + (size_t)(nBase + srow) * ldb + cs * 8;
  int ldso = w * 512 + l * 8;              // shorts

  int NT = K >> 6;
#define STAGE(tt, buf)                                                         \
  {                                                                            \
    _Pragma("unroll") for (int i = 0; i < 4; ++i) {                            \
      g2l16(Ag + (size_t)(i * 32) * lda + (tt) * 64, &As[buf][i * 2048 + ldso]); \
      g2l16(Bg + (size_t)(i * 32) * ldb + (tt) * 64, &Bs[buf][i * 2048 + ldso]); \
    }                                                                          \
  }

  STAGE(0, 0);

  int wr = (w >> 1) * 64, wc = (w & 1) * 64;
  int c0 = l & 15, kg = l >> 4, cx = l & 7;
  f32x4 zero = {0.f, 0.f, 0.f, 0.f};
  f32x4 acc[4][4];
#pragma unroll
  for (int m = 0; m < 4; ++m)
#pragma unroll
    for (int n = 0; n < 4; ++n) acc[m][n] = zero;

  asm volatile("s_waitcnt vmcnt(0)\ns_barrier" ::: "memory");  // tile 0 ready

  for (int kt = 0; kt < NT; ++kt) {
    if (kt + 1 < NT) STAGE(kt + 1, (kt + 1) & 1);   // overwrites buffer freed at last barrier
    const short* Ab = As[kt & 1];
    const short* Bb = Bs[kt & 1];
    short8 af[4][2], bfr[4][2];
#pragma unroll
    for (int m = 0; m < 4; ++m)
#pragma unroll
      for (int kk = 0; kk < 2; ++kk)
        af[m][kk] = *(const short8*)(Ab + (wr + m * 16 + c0) * 64 + ((kk * 4 + kg) ^ cx) * 8);
#pragma unroll
    for (int n = 0; n < 4; ++n)
#pragma unroll
      for (int kk = 0; kk < 2; ++kk)
        bfr[n][kk] = *(const short8*)(Bb + (wc + n * 16 + c0) * 64 + ((kk * 4 + kg) ^ cx) * 8);
    __builtin_amdgcn_s_setprio(1);
#pragma unroll
    for (int m = 0; m < 4; ++m)
#pragma unroll
      for (int n = 0; n < 4; ++n)
#pragma unroll
        for (int kk = 0; kk < 2; ++kk)
          acc[m][n] = __builtin_amdgcn_mfma_f32_16x16x32_bf16(af[m][kk], bfr[n][kk],
                                                              acc[m][n], 0, 0, 0);
    __builtin_amdgcn_s_setprio(0);
    // next tile landed + all waves' ds_reads of this tile done
    asm volatile("s_waitcnt vmcnt(0)\ns_barrier" ::: "memory");
  }
#undef STAGE

  int r0 = (l >> 4) * 4;
#pragma unroll
  for (int m = 0; m < 4; ++m)
#pragma unroll
    for (int n = 0; n < 4; ++n)
#pragma unroll
      for (int r = 0; r < 4; ++r) {
        float val = acc[m][n][r];
        int row = mBase + wr + m * 16 + r0 + r;
        int col = nBase + wc + n * 16 + c0;
        if (MODE == 0) {
          if (col < AINNER)
            ((short*)out0)[(size_t)row * AINNER + col] = f2bf(val);
          else if (col < AINNER + DH)
            ((short*)out1)[(size_t)row * DH + (col - AINNER)] = f2bf(val);
          else if (col < AINNER + 2 * DH)
            ((short*)out2)[((size_t)(row >> 11) * DH + (col - AINNER - DH)) * SEQ +
                           (row & (SEQ - 1))] = f2bf(val);
          else
            ((short*)out3)[(size_t)row * HCOLS + AINNER + (col - 640)] = f2bf(val);
        } else if (MODE == 1) {
          short* Hp = (short*)out0;
          size_t idx = (size_t)row * HCOLS + AINNER + col;
          float sg = val / (1.f + __expf(-val));
          Hp[idx] = f2bf(sg * bf2f(Hp[idx]));
        } else {
          ((float*)out0)[(size_t)row * DIM + col] = val;
        }
      }
}

// ---------------- flash attention: 64-query tile, 2 blocks/CU ---------------
__global__ __launch_bounds__(256) void k_attn(const short* __restrict__ qb,
                                              const short* __restrict__ kb,
                                              const short* __restrict__ vt,
                                              short* __restrict__ H) {
  __shared__ __align__(16) short Qs[64 * 64];
  __shared__ __align__(16) short Ks[128 * 64];
  __shared__ __align__(16) short Vs[64 * 128];
  __shared__ __align__(16) short Ps[4][16 * 128];
  int t = threadIdx.x, l = t & 63, w = t >> 6;
  int qt = blockIdx.x, bh = blockIdx.y;
  int b = bh >> 3, h = bh & 7;
  int q0 = qt * 64;

  int srow = w * 8 + (l >> 3);
  int schunk = (l & 7) ^ (l >> 3);
  {
    const short* Qg = qb + (size_t)(b * SEQ + q0 + srow) * AINNER + h * DH + schunk * 8;
    short* qs = Qs + w * 512 + l * 8;
#pragma unroll
    for (int i = 0; i < 2; ++i) g2l16(Qg + (size_t)(i * 32) * AINNER, qs + i * 2048);
  }
  const short* Kg = kb + (size_t)(b * SEQ + srow) * DH + schunk * 8;
  short* ksl = Ks + w * 512 + l * 8;
  int vrow = w * 4 + (l >> 4);
  int vchunk = (l & 15) ^ (vrow & 7);
  const short* Vg = vt + (size_t)b * DH * SEQ + (size_t)vrow * SEQ + vchunk * 8;
  short* vsl = Vs + w * 512 + l * 8;

#pragma unroll
  for (int i = 0; i < 4; ++i) {
    g2l16(Kg + (size_t)(i * 32) * DH, ksl + i * 2048);
    g2l16(Vg + (size_t)(i * 16) * SEQ, vsl + i * 2048);
  }

  float m_run[4], l_run[4];
  f32x4 zero = {0.f, 0.f, 0.f, 0.f};
  f32x4 Oacc[4];
#pragma unroll
  for (int r = 0; r < 4; ++r) { m_run[r] = -1e30f; l_run[r] = 0.f; }
#pragma unroll
  for (int n = 0; n < 4; ++n) Oacc[n] = zero;

  int c0 = l & 15, kg = l >> 4, cx = l & 7;
  short* pw = Ps[w];

  for (int kv0 = 0; kv0 < SEQ; kv0 += 128) {
    asm volatile("s_waitcnt vmcnt(0)\ns_barrier" ::: "memory");

    f32x4 sacc[8];
#pragma unroll
    for (int n = 0; n < 8; ++n) sacc[n] = zero;
#pragma unroll
    for (int kk = 0; kk < 2; ++kk) {
      int rr = w * 16 + c0;
      short8 aq = *(const short8*)(Qs + rr * 64 + ((kk * 4 + kg) ^ cx) * 8);
#pragma unroll
      for (int n = 0; n < 8; ++n) {
        int kr = n * 16 + c0;
        short8 bk = *(const short8*)(Ks + kr * 64 + ((kk * 4 + kg) ^ cx) * 8);
        sacc[n] = __builtin_amdgcn_mfma_f32_16x16x32_bf16(aq, bk, sacc[n], 0, 0, 0);
      }
    }
#pragma unroll
    for (int r = 0; r < 4; ++r) {
      float mx = -1e30f;
#pragma unroll
      for (int n = 0; n < 8; ++n) {
        sacc[n][r] *= 0.125f;
        mx = fmaxf(mx, sacc[n][r]);
      }
#pragma unroll
      for (int msk = 1; msk < 16; msk <<= 1) mx = fmaxf(mx, __shfl_xor(mx, msk));
      float nm = fmaxf(m_run[r], mx);
      float corr = __expf(m_run[r] - nm);
      m_run[r] = nm;
      float rs = 0.f;
#pragma unroll
      for (int n = 0; n < 8; ++n) {
        float p = __expf(sacc[n][r] - nm);
        sacc[n][r] = p;
        rs += p;
      }
#pragma unroll
      for (int msk = 1; msk < 16; msk <<= 1) rs += __shfl_xor(rs, msk);
      l_run[r] = l_run[r] * corr + rs;
      Oacc[0][r] *= corr; Oacc[1][r] *= corr; Oacc[2][r] *= corr; Oacc[3][r] *= corr;
    }
#pragma unroll
    for (int n = 0; n < 8; ++n)
#pragma unroll
      for (int r = 0; r < 4; ++r) {
        int pr = (l >> 4) * 4 + r;
        int pc = n * 16 + c0;
        pw[pr * 128 + ((pc >> 3) ^ (pr & 7)) * 8 + (pc & 7)] = f2bf(sacc[n][r]);
      }
    asm volatile("s_waitcnt lgkmcnt(0)" ::: "memory");
#pragma unroll
    for (int kk = 0; kk < 4; ++kk) {
      int pr = c0;
      short8 ap = *(const short8*)(pw + pr * 128 + ((kk * 4 + kg) ^ cx) * 8);
#pragma unroll
      for (int n = 0; n < 4; ++n) {
        int vr = n * 16 + c0;
        short8 bv = *(const short8*)(Vs + vr * 128 + ((kk * 4 + kg) ^ (vr & 7)) * 8);
        Oacc[n] = __builtin_amdgcn_mfma_f32_16x16x32_bf16(ap, bv, Oacc[n], 0, 0, 0);
      }
    }
    __syncthreads();
    int nx = kv0 + 128;
    if (nx < SEQ) {
#pragma unroll
      for (int i = 0; i < 4; ++i) {
        g2l16(Kg + (size_t)(nx + i * 32) * DH, ksl + i * 2048);
        g2l16(Vg + nx + (size_t)(i * 16) * SEQ, vsl + i * 2048);
      }
    }
  }
#pragma unroll
  for (int r = 0; r < 4; ++r) {
    float inv = 1.f / l_run[r];
    int row = b * SEQ + q0 + w * 16 + (l >> 4) * 4 + r;
#pragma unroll
    for (int n = 0; n < 4; ++n) {
      int col = h * DH + n * 16 + c0;
      H[(size_t)row * HCOLS + col] = f2bf(Oacc[n][r] * inv);
    }
  }
}

// ----------------------------------------------------------------------------
extern "C" void kernel_launch(void* const* d_in, const int* in_sizes, int n_in,
                              void* d_out, int out_size, void* d_ws, size_t ws_size,
                              hipStream_t stream) {
  const float* x     = (const float*)d_in[0];
  const float* gamma = (const float*)d_in[1];
  const float* w_f   = (const float*)d_in[2];
  const float* w_ao  = (const float*)d_in[3];
  const float* w_fo  = (const float*)d_in[4];
  float* out = (float*)d_out;

  char* ws = (char*)d_ws;
  size_t o = 0;
  short* WtF = (short*)(ws + o); o += (size_t)FUSED * DIM * 2;
  short* Wt2 = (short*)(ws + o); o += (size_t)DIM * HCOLS * 2;
  short* xn  = (short*)(ws + o); o += (size_t)NTOK * DIM * 2;
  short* qb  = (short*)(ws + o); o += (size_t)NTOK * AINNER * 2;
  short* kbf = (short*)(ws + o); o += (size_t)NTOK * DH * 2;
  short* vtb = (short*)(ws + o); o += (size_t)NTOK * DH * 2;
  short* H   = (short*)(ws + o); o += (size_t)NTOK * HCOLS * 2;

  k_transpose_wf<<<dim3(FUSED / 32, DIM / 32), 256, 0, stream>>>(w_f, WtF);
  k_transpose_w2<<<dim3(DIM / 32, HCOLS / 32), 256, 0, stream>>>(w_ao, w_fo, Wt2);
  k_ln<<<NTOK, 256, 0, stream>>>(x, gamma, xn);
  gemm_p<0><<<dim3(37, 32), 256, 0, stream>>>(xn, DIM, WtF, DIM, DIM,
                                              qb, kbf, vtb, H);
  k_attn<<<dim3(32, 16), 256, 0, stream>>>(qb, kbf, vtb, H);
  gemm_p<1><<<dim3(32, 32), 256, 0, stream>>>(xn, DIM, WtF + (size_t)4736 * DIM, DIM,
                                              DIM, H, nullptr, nullptr, nullptr);
  gemm_p<2><<<dim3(8, 32), 256, 0, stream>>>(H, HCOLS, Wt2, HCOLS, HCOLS, out,
                                             nullptr, nullptr, nullptr);
}

// Round 6
// 241.901 us; speedup vs baseline: 1.1276x; 1.1276x over previous
//
#include <hip/hip_runtime.h>
#include <hip/hip_bf16.h>
#include <stdint.h>

#define DIM     1024
#define SEQ     2048
#define NTOK    4096
#define HEADS   8
#define DH      64
#define AINNER  512
#define FFI     4096
#define FUSED   8832
#define HCOLS   4608   // 512 attn-out cols + 4096 gated-ff cols

typedef __attribute__((ext_vector_type(8))) short short8;
typedef __attribute__((ext_vector_type(4))) short short4v;
typedef __attribute__((ext_vector_type(4))) float f32x4;

__device__ __forceinline__ short f2bf(float f) {
  union { float f; uint32_t u; } v; v.f = f;
  uint32_t r = v.u + 0x7fffu + ((v.u >> 16) & 1u);
  return (short)(r >> 16);
}
__device__ __forceinline__ float bf2f(short s) {
  union { uint32_t u; float f; } v; v.u = ((uint32_t)(uint16_t)s) << 16;
  return v.f;
}
__device__ __forceinline__ void g2l16(const void* g, void* l) {
  __builtin_amdgcn_global_load_lds((const __attribute__((address_space(1))) void*)g,
                                   (__attribute__((address_space(3))) void*)l, 16, 0, 0);
}

// ---------------- transpose + f32->bf16 convert -----------------------------
__global__ __launch_bounds__(256) void k_transpose_wf(const float* __restrict__ src,
                                                      short* __restrict__ dst) {
  __shared__ short tile[32][33];
  int c0 = blockIdx.x * 32;
  int r0 = blockIdx.y * 32;
  int tx = threadIdx.x & 31, ty = threadIdx.x >> 5;
#pragma unroll
  for (int i = 0; i < 32; i += 8)
    tile[ty + i][tx] = f2bf(src[(size_t)(r0 + ty + i) * FUSED + c0 + tx]);
  __syncthreads();
#pragma unroll
  for (int i = 0; i < 32; i += 8)
    dst[(size_t)(c0 + ty + i) * DIM + r0 + tx] = tile[tx][ty + i];
}

__global__ __launch_bounds__(256) void k_transpose_w2(const float* __restrict__ wao,
                                                      const float* __restrict__ wfo,
                                                      short* __restrict__ dst) {
  __shared__ short tile[32][33];
  int c0 = blockIdx.x * 32;
  int r0 = blockIdx.y * 32;
  int tx = threadIdx.x & 31, ty = threadIdx.x >> 5;
#pragma unroll
  for (int i = 0; i < 32; i += 8) {
    int r = r0 + ty + i;
    float v = (r < AINNER) ? wao[(size_t)r * DIM + c0 + tx]
                           : wfo[(size_t)(r - AINNER) * DIM + c0 + tx];
    tile[ty + i][tx] = f2bf(v);
  }
  __syncthreads();
#pragma unroll
  for (int i = 0; i < 32; i += 8)
    dst[(size_t)(c0 + ty + i) * HCOLS + r0 + tx] = tile[tx][ty + i];
}

// ---------------- layernorm -------------------------------------------------
__global__ __launch_bounds__(256) void k_ln(const float* __restrict__ x,
                                            const float* __restrict__ gamma,
                                            short* __restrict__ xn) {
  int row = blockIdx.x;
  int t = threadIdx.x;
  const float4* xr = (const float4*)(x + (size_t)row * DIM);
  float4 v = xr[t];
  float s = v.x + v.y + v.z + v.w;
  float s2 = v.x * v.x + v.y * v.y + v.z * v.z + v.w * v.w;
#pragma unroll
  for (int m = 1; m < 64; m <<= 1) { s += __shfl_xor(s, m); s2 += __shfl_xor(s2, m); }
  __shared__ float red[8];
  int w = t >> 6;
  if ((t & 63) == 0) { red[w] = s; red[4 + w] = s2; }
  __syncthreads();
  s = red[0] + red[1] + red[2] + red[3];
  s2 = red[4] + red[5] + red[6] + red[7];
  float mu = s * (1.f / DIM);
  float rs = rsqrtf(s2 * (1.f / DIM) - mu * mu + 1e-5f);
  const float4* g4 = (const float4*)gamma;
  float4 g = g4[t];
  short4v o;
  o.x = f2bf((v.x - mu) * rs * g.x);
  o.y = f2bf((v.y - mu) * rs * g.y);
  o.z = f2bf((v.z - mu) * rs * g.z);
  o.w = f2bf((v.w - mu) * rs * g.w);
  ((short4v*)(xn + (size_t)row * DIM))[t] = o;
}

// ---------------- 256x256 4-phase-per-K-tile GEMM ---------------------------
// 512 thr = 8 waves (2M x 4N), wave tile 128x64, BK=64, 128KB dyn LDS dbuf.
// Per K-tile: tile-start {vmcnt(0); barrier}; 4 phases: {ds_read quad ||
// stage 1 half-tile of kt+1 -> other buf; barrier; setprio1; 16 MFMA; setprio0}.
// LDS (shorts): A halves at (db*2+h)*8192; B halves at 32768 + (db*2+h)*8192.
// MODE 0: qkv+ffx split write (skip col>=4736); 1: H = silu(gate)*H (RMW).
template <int MODE>
__global__ __launch_bounds__(512, 2) void gemm8(const short* __restrict__ A, int lda,
                                                const short* __restrict__ Bt, int ldb,
                                                int K, void* __restrict__ out0,
                                                void* __restrict__ out1,
                                                void* __restrict__ out2,
                                                void* __restrict__ out3) {
  extern __shared__ __align__(16) short S[];
  int tid = threadIdx.x, l = tid & 63, w = tid >> 6;
  int wm = w >> 2, wn = w & 3;
  int gx = gridDim.x, nwg = gx * gridDim.y;
  int hw = blockIdx.y * gx + blockIdx.x;
  int qq = nwg >> 3;                       // grids divisible by 8
  int tile = (hw & 7) * qq + (hw >> 3);    // XCD-contiguous remap
  int bx = tile % gx, by = tile / gx;
  int mBase = by * 256, nBase = bx * 256;

  // staging: inst covers 64 rows; wave w rows w*8+(l>>3); chunk (l&7)^(l>>3)
  int srow = w * 8 + (l >> 3);
  int cs = (l & 7) ^ (l >> 3);
  const short* Ag = A + (size_t)(mBase + srow) * lda + cs * 8;
  const short* Bg = Bt + (size_t)(nBase + srow) * ldb + cs * 8;
  int dsto = w * 512 + l * 8;              // shorts

#define STG_A(kt, h, db)                                                        \
  {                                                                             \
    g2l16(Ag + (size_t)((h) * 128) * lda + (kt) * 64,                           \
          S + ((db) * 2 + (h)) * 8192 + dsto);                                  \
    g2l16(Ag + (size_t)((h) * 128 + 64) * lda + (kt) * 64,                      \
          S + ((db) * 2 + (h)) * 8192 + 4096 + dsto);                           \
  }
#define STG_B(kt, h, db)                                                        \
  {                                                                             \
    g2l16(Bg + (size_t)((h) * 128) * ldb + (kt) * 64,                           \
          S + 32768 + ((db) * 2 + (h)) * 8192 + dsto);                          \
    g2l16(Bg + (size_t)((h) * 128 + 64) * ldb + (kt) * 64,                      \
          S + 32768 + ((db) * 2 + (h)) * 8192 + 4096 + dsto);                   \
  }

  int NT = K >> 6;
  STG_A(0, 0, 0); STG_A(0, 1, 0); STG_B(0, 0, 0); STG_B(0, 1, 0);

  int c0 = l & 15, kg = l >> 4, cx = l & 7;
  f32x4 zero = {0.f, 0.f, 0.f, 0.f};
  f32x4 acc[8][4];
#pragma unroll
  for (int m = 0; m < 8; ++m)
#pragma unroll
    for (int n = 0; n < 4; ++n) acc[m][n] = zero;

  int brow = (wn & 1) * 64;                // B row base within half

  for (int kt = 0; kt < NT; ++kt) {
    int db = kt & 1, dbn = db ^ 1;
    const short* Ab = S + (db * 2 + wm) * 8192;
    const short* Bb = S + 32768 + (db * 2 + (wn >> 1)) * 8192;
    int ts = kt + 1;
    bool st = ts < NT;
    // tile kt fully resident; all waves done reading buffer dbn (freed)
    asm volatile("s_waitcnt vmcnt(0)\ns_barrier" ::: "memory");

    short8 b0[4], b1[4], a[4];
    // ---- phase 0: kk=0, m 0..3 ----
#pragma unroll
    for (int n = 0; n < 4; ++n)
      b0[n] = *(const short8*)(Bb + (brow + n * 16 + c0) * 64 + (kg ^ cx) * 8);
#pragma unroll
    for (int mi = 0; mi < 4; ++mi)
      a[mi] = *(const short8*)(Ab + (mi * 16 + c0) * 64 + (kg ^ cx) * 8);
    if (st) STG_A(ts, 0, dbn);
    asm volatile("s_barrier" ::: "memory");
    __builtin_amdgcn_s_setprio(1);
#pragma unroll
    for (int mi = 0; mi < 4; ++mi)
#pragma unroll
      for (int n = 0; n < 4; ++n)
        acc[mi][n] = __builtin_amdgcn_mfma_f32_16x16x32_bf16(a[mi], b0[n], acc[mi][n], 0, 0, 0);
    __builtin_amdgcn_s_setprio(0);
    // ---- phase 1: kk=0, m 4..7 ----
#pragma unroll
    for (int mi = 0; mi < 4; ++mi)
      a[mi] = *(const short8*)(Ab + ((4 + mi) * 16 + c0) * 64 + (kg ^ cx) * 8);
    if (st) STG_A(ts, 1, dbn);
    asm volatile("s_barrier" ::: "memory");
    __builtin_amdgcn_s_setprio(1);
#pragma unroll
    for (int mi = 0; mi < 4; ++mi)
#pragma unroll
      for (int n = 0; n < 4; ++n)
        acc[4 + mi][n] = __builtin_amdgcn_mfma_f32_16x16x32_bf16(a[mi], b0[n], acc[4 + mi][n], 0, 0, 0);
    __builtin_amdgcn_s_setprio(0);
    // ---- phase 2: kk=1, m 0..3 ----
#pragma unroll
    for (int n = 0; n < 4; ++n)
      b1[n] = *(const short8*)(Bb + (brow + n * 16 + c0) * 64 + ((4 + kg) ^ cx) * 8);
#pragma unroll
    for (int mi = 0; mi < 4; ++mi)
      a[mi] = *(const short8*)(Ab + (mi * 16 + c0) * 64 + ((4 + kg) ^ cx) * 8);
    if (st) STG_B(ts, 0, dbn);
    asm volatile("s_barrier" ::: "memory");
    __builtin_amdgcn_s_setprio(1);
#pragma unroll
    for (int mi = 0; mi < 4; ++mi)
#pragma unroll
      for (int n = 0; n < 4; ++n)
        acc[mi][n] = __builtin_amdgcn_mfma_f32_16x16x32_bf16(a[mi], b1[n], acc[mi][n], 0, 0, 0);
    __builtin_amdgcn_s_setprio(0);
    // ---- phase 3: kk=1, m 4..7 ----
#pragma unroll
    for (int mi = 0; mi < 4; ++mi)
      a[mi] = *(const short8*)(Ab + ((4 + mi) * 16 + c0) * 64 + ((4 + kg) ^ cx) * 8);
    if (st) STG_B(ts, 1, dbn);
    asm volatile("s_barrier" ::: "memory");
    __builtin_amdgcn_s_setprio(1);
#pragma unroll
    for (int mi = 0; mi < 4; ++mi)
#pragma unroll
      for (int n = 0; n < 4; ++n)
        acc[4 + mi][n] = __builtin_amdgcn_mfma_f32_16x16x32_bf16(a[mi], b1[n], acc[4 + mi][n], 0, 0, 0);
    __builtin_amdgcn_s_setprio(0);
  }
#undef STG_A
#undef STG_B

  int r0 = (l >> 4) * 4;
#pragma unroll
  for (int m = 0; m < 8; ++m)
#pragma unroll
    for (int n = 0; n < 4; ++n)
#pragma unroll
      for (int r = 0; r < 4; ++r) {
        float val = acc[m][n][r];
        int row = mBase + wm * 128 + m * 16 + r0 + r;
        int col = nBase + wn * 64 + n * 16 + c0;
        if (MODE == 0) {
          if (col < AINNER)
            ((short*)out0)[(size_t)row * AINNER + col] = f2bf(val);
          else if (col < AINNER + DH)
            ((short*)out1)[(size_t)row * DH + (col - AINNER)] = f2bf(val);
          else if (col < AINNER + 2 * DH)
            ((short*)out2)[((size_t)(row >> 11) * DH + (col - AINNER - DH)) * SEQ +
                           (row & (SEQ - 1))] = f2bf(val);
          else if (col < 4736)
            ((short*)out3)[(size_t)row * HCOLS + AINNER + (col - 640)] = f2bf(val);
          // col >= 4736: padding tile, skip
        } else {
          short* Hp = (short*)out0;
          size_t idx = (size_t)row * HCOLS + AINNER + col;
          float sg = val / (1.f + __expf(-val));
          Hp[idx] = f2bf(sg * bf2f(Hp[idx]));
        }
      }
}

// ---------------- ring-4 counted-vmcnt 128x128 GEMM (f32 out) ---------------
__global__ __launch_bounds__(512, 2) void gemm_r(const short* __restrict__ A, int lda,
                                                 const short* __restrict__ Bt, int ldb,
                                                 int K, float* __restrict__ out0) {
  extern __shared__ __align__(16) short SA[];
  int tid = threadIdx.x, l = tid & 63, w = tid >> 6;
  int gx = gridDim.x;
  int nwg = gx * gridDim.y;
  int hw = blockIdx.y * gx + blockIdx.x;
  int qq = nwg >> 3;
  int tile = (hw & 7) * qq + (hw >> 3);
  int bx = tile % gx, by = tile / gx;
  int mBase = by * 128, nBase = bx * 128;

  int srow = w * 8 + (l >> 3);
  int cs = (l & 7) ^ (l >> 3);
  const short* Ag = A + (size_t)(mBase + srow) * lda + cs * 8;
  const short* Bg = Bt + (size_t)(nBase + srow) * ldb + cs * 8;
  short* ldsA = SA + w * 512 + l * 8;
  short* ldsB = ldsA + 8192;

  int NT = K >> 6;
  for (int tt = 0; tt < 3; ++tt) {
    int slot = tt & 3;
#pragma unroll
    for (int i = 0; i < 2; ++i) {
      g2l16(Ag + (size_t)(i * 64) * lda + tt * 64, ldsA + slot * 16384 + i * 4096);
      g2l16(Bg + (size_t)(i * 64) * ldb + tt * 64, ldsB + slot * 16384 + i * 4096);
    }
  }

  int wr = w >> 2, wc = w & 3;
  int c0 = l & 15, kg = l >> 4, cx = l & 7;
  f32x4 zero = {0.f, 0.f, 0.f, 0.f};
  f32x4 acc[4][2];
#pragma unroll
  for (int m = 0; m < 4; ++m)
#pragma unroll
    for (int n = 0; n < 2; ++n) acc[m][n] = zero;

  for (int kt = 0; kt < NT; ++kt) {
    if (kt + 2 < NT)      asm volatile("s_waitcnt vmcnt(8)\ns_barrier" ::: "memory");
    else if (kt + 1 < NT) asm volatile("s_waitcnt vmcnt(4)\ns_barrier" ::: "memory");
    else                  asm volatile("s_waitcnt vmcnt(0)\ns_barrier" ::: "memory");
    int slot = kt & 3;
    const short* Ab = SA + slot * 16384;
    const short* Bb = Ab + 8192;
    short8 af[4][2], bfr[2][2];
#pragma unroll
    for (int m = 0; m < 4; ++m)
#pragma unroll
      for (int kk = 0; kk < 2; ++kk)
        af[m][kk] = *(const short8*)(Ab + (wr * 64 + m * 16 + c0) * 64 + ((kk * 4 + kg) ^ cx) * 8);
#pragma unroll
    for (int n = 0; n < 2; ++n)
#pragma unroll
      for (int kk = 0; kk < 2; ++kk)
        bfr[n][kk] = *(const short8*)(Bb + (wc * 32 + n * 16 + c0) * 64 + ((kk * 4 + kg) ^ cx) * 8);
    int ts = kt + 3;
    if (ts < NT) {
      int s2 = ts & 3;
#pragma unroll
      for (int i = 0; i < 2; ++i) {
        g2l16(Ag + (size_t)(i * 64) * lda + ts * 64, ldsA + s2 * 16384 + i * 4096);
        g2l16(Bg + (size_t)(i * 64) * ldb + ts * 64, ldsB + s2 * 16384 + i * 4096);
      }
    }
    __builtin_amdgcn_s_setprio(1);
#pragma unroll
    for (int m = 0; m < 4; ++m)
#pragma unroll
      for (int n = 0; n < 2; ++n)
#pragma unroll
        for (int kk = 0; kk < 2; ++kk)
          acc[m][n] = __builtin_amdgcn_mfma_f32_16x16x32_bf16(af[m][kk], bfr[n][kk],
                                                              acc[m][n], 0, 0, 0);
    __builtin_amdgcn_s_setprio(0);
  }

  int r0 = (l >> 4) * 4;
#pragma unroll
  for (int m = 0; m < 4; ++m)
#pragma unroll
    for (int n = 0; n < 2; ++n)
#pragma unroll
      for (int r = 0; r < 4; ++r) {
        int row = mBase + wr * 64 + m * 16 + r0 + r;
        int col = nBase + wc * 32 + n * 16 + c0;
        out0[(size_t)row * DIM + col] = acc[m][n][r];
      }
}

// ---------------- flash attention: 64-query tile, 2 blocks/CU ---------------
__global__ __launch_bounds__(256) void k_attn(const short* __restrict__ qb,
                                              const short* __restrict__ kb,
                                              const short* __restrict__ vt,
                                              short* __restrict__ H) {
  __shared__ __align__(16) short Qs[64 * 64];
  __shared__ __align__(16) short Ks[128 * 64];
  __shared__ __align__(16) short Vs[64 * 128];
  __shared__ __align__(16) short Ps[4][16 * 128];
  int t = threadIdx.x, l = t & 63, w = t >> 6;
  int qt = blockIdx.x, bh = blockIdx.y;
  int b = bh >> 3, h = bh & 7;
  int q0 = qt * 64;

  int srow = w * 8 + (l >> 3);
  int schunk = (l & 7) ^ (l >> 3);
  {
    const short* Qg = qb + (size_t)(b * SEQ + q0 + srow) * AINNER + h * DH + schunk * 8;
    short* qs = Qs + w * 512 + l * 8;
#pragma unroll
    for (int i = 0; i < 2; ++i) g2l16(Qg + (size_t)(i * 32) * AINNER, qs + i * 2048);
  }
  const short* Kg = kb + (size_t)(b * SEQ + srow) * DH + schunk * 8;
  short* ksl = Ks + w * 512 + l * 8;
  int vrow = w * 4 + (l >> 4);
  int vchunk = (l & 15) ^ (vrow & 7);
  const short* Vg = vt + (size_t)b * DH * SEQ + (size_t)vrow * SEQ + vchunk * 8;
  short* vsl = Vs + w * 512 + l * 8;

#pragma unroll
  for (int i = 0; i < 4; ++i) {
    g2l16(Kg + (size_t)(i * 32) * DH, ksl + i * 2048);
    g2l16(Vg + (size_t)(i * 16) * SEQ, vsl + i * 2048);
  }

  float m_run[4], l_run[4];
  f32x4 zero = {0.f, 0.f, 0.f, 0.f};
  f32x4 Oacc[4];
#pragma unroll
  for (int r = 0; r < 4; ++r) { m_run[r] = -1e30f; l_run[r] = 0.f; }
#pragma unroll
  for (int n = 0; n < 4; ++n) Oacc[n] = zero;

  int c0 = l & 15, kg = l >> 4, cx = l & 7;
  short* pw = Ps[w];

  for (int kv0 = 0; kv0 < SEQ; kv0 += 128) {
    asm volatile("s_waitcnt vmcnt(0)\ns_barrier" ::: "memory");

    f32x4 sacc[8];
#pragma unroll
    for (int n = 0; n < 8; ++n) sacc[n] = zero;
#pragma unroll
    for (int kk = 0; kk < 2; ++kk) {
      int rr = w * 16 + c0;
      short8 aq = *(const short8*)(Qs + rr * 64 + ((kk * 4 + kg) ^ cx) * 8);
#pragma unroll
      for (int n = 0; n < 8; ++n) {
        int kr = n * 16 + c0;
        short8 bk = *(const short8*)(Ks + kr * 64 + ((kk * 4 + kg) ^ cx) * 8);
        sacc[n] = __builtin_amdgcn_mfma_f32_16x16x32_bf16(aq, bk, sacc[n], 0, 0, 0);
      }
    }
#pragma unroll
    for (int r = 0; r < 4; ++r) {
      float mx = -1e30f;
#pragma unroll
      for (int n = 0; n < 8; ++n) {
        sacc[n][r] *= 0.125f;
        mx = fmaxf(mx, sacc[n][r]);
      }
#pragma unroll
      for (int msk = 1; msk < 16; msk <<= 1) mx = fmaxf(mx, __shfl_xor(mx, msk));
      float nm = fmaxf(m_run[r], mx);
      float corr = __expf(m_run[r] - nm);
      m_run[r] = nm;
      float rs = 0.f;
#pragma unroll
      for (int n = 0; n < 8; ++n) {
        float p = __expf(sacc[n][r] - nm);
        sacc[n][r] = p;
        rs += p;
      }
#pragma unroll
      for (int msk = 1; msk < 16; msk <<= 1) rs += __shfl_xor(rs, msk);
      l_run[r] = l_run[r] * corr + rs;
      Oacc[0][r] *= corr; Oacc[1][r] *= corr; Oacc[2][r] *= corr; Oacc[3][r] *= corr;
    }
#pragma unroll
    for (int n = 0; n < 8; ++n)
#pragma unroll
      for (int r = 0; r < 4; ++r) {
        int pr = (l >> 4) * 4 + r;
        int pc = n * 16 + c0;
        pw[pr * 128 + ((pc >> 3) ^ (pr & 7)) * 8 + (pc & 7)] = f2bf(sacc[n][r]);
      }
    asm volatile("s_waitcnt lgkmcnt(0)" ::: "memory");
#pragma unroll
    for (int kk = 0; kk < 4; ++kk) {
      int pr = c0;
      short8 ap = *(const short8*)(pw + pr * 128 + ((kk * 4 + kg) ^ cx) * 8);
#pragma unroll
      for (int n = 0; n < 4; ++n) {
        int vr = n * 16 + c0;
        short8 bv = *(const short8*)(Vs + vr * 128 + ((kk * 4 + kg) ^ (vr & 7)) * 8);
        Oacc[n] = __builtin_amdgcn_mfma_f32_16x16x32_bf16(ap, bv, Oacc[n], 0, 0, 0);
      }
    }
    __syncthreads();
    int nx = kv0 + 128;
    if (nx < SEQ) {
#pragma unroll
      for (int i = 0; i < 4; ++i) {
        g2l16(Kg + (size_t)(nx + i * 32) * DH, ksl + i * 2048);
        g2l16(Vg + nx + (size_t)(i * 16) * SEQ, vsl + i * 2048);
      }
    }
  }
#pragma unroll
  for (int r = 0; r < 4; ++r) {
    float inv = 1.f / l_run[r];
    int row = b * SEQ + q0 + w * 16 + (l >> 4) * 4 + r;
#pragma unroll
    for (int n = 0; n < 4; ++n) {
      int col = h * DH + n * 16 + c0;
      H[(size_t)row * HCOLS + col] = f2bf(Oacc[n][r] * inv);
    }
  }
}

// ----------------------------------------------------------------------------
extern "C" void kernel_launch(void* const* d_in, const int* in_sizes, int n_in,
                              void* d_out, int out_size, void* d_ws, size_t ws_size,
                              hipStream_t stream) {
  const float* x     = (const float*)d_in[0];
  const float* gamma = (const float*)d_in[1];
  const float* w_f   = (const float*)d_in[2];
  const float* w_ao  = (const float*)d_in[3];
  const float* w_fo  = (const float*)d_in[4];
  float* out = (float*)d_out;

  char* ws = (char*)d_ws;
  size_t o = 0;
  short* WtF = (short*)(ws + o); o += (size_t)FUSED * DIM * 2;
  short* Wt2 = (short*)(ws + o); o += (size_t)DIM * HCOLS * 2;
  short* xn  = (short*)(ws + o); o += (size_t)NTOK * DIM * 2;
  short* qb  = (short*)(ws + o); o += (size_t)NTOK * AINNER * 2;
  short* kbf = (short*)(ws + o); o += (size_t)NTOK * DH * 2;
  short* vtb = (short*)(ws + o); o += (size_t)NTOK * DH * 2;
  short* H   = (short*)(ws + o); o += (size_t)NTOK * HCOLS * 2;

  k_transpose_wf<<<dim3(FUSED / 32, DIM / 32), 256, 0, stream>>>(w_f, WtF);
  k_transpose_w2<<<dim3(DIM / 32, HCOLS / 32), 256, 0, stream>>>(w_ao, w_fo, Wt2);
  k_ln<<<NTOK, 256, 0, stream>>>(x, gamma, xn);
  // q,k,v,ffx: fused cols 0..4735 (N padded to 4864 = 19 tiles; pad cols skipped)
  gemm8<0><<<dim3(19, 16), 512, 131072, stream>>>(xn, DIM, WtF, DIM, DIM,
                                                  qb, kbf, vtb, H);
  k_attn<<<dim3(32, 16), 256, 0, stream>>>(qb, kbf, vtb, H);
  // gate: fused cols 4736..8831 -> H = silu(gate) * H
  gemm8<1><<<dim3(16, 16), 512, 131072, stream>>>(xn, DIM, WtF + (size_t)4736 * DIM, DIM,
                                                  DIM, H, nullptr, nullptr, nullptr);
  // out = H (4096x4608) @ [w_attn_out; w_ff_out]
  gemm_r<<<dim3(8, 32), 512, 131072, stream>>>(H, HCOLS, Wt2, HCOLS, HCOLS, out);
}

// Round 7
// 231.854 us; speedup vs baseline: 1.1764x; 1.0433x over previous
//
#include <hip/hip_runtime.h>
#include <hip/hip_bf16.h>
#include <stdint.h>

#define DIM     1024
#define SEQ     2048
#define NTOK    4096
#define HEADS   8
#define DH      64
#define AINNER  512
#define FFI     4096
#define FUSED   8832
#define HCOLS   4608   // 512 attn-out cols + 4096 gated-ff cols

typedef __attribute__((ext_vector_type(8))) short short8;
typedef __attribute__((ext_vector_type(4))) short short4v;
typedef __attribute__((ext_vector_type(4))) float f32x4;

__device__ __forceinline__ short f2bf(float f) {
  union { float f; uint32_t u; } v; v.f = f;
  uint32_t r = v.u + 0x7fffu + ((v.u >> 16) & 1u);
  return (short)(r >> 16);
}
__device__ __forceinline__ float bf2f(short s) {
  union { uint32_t u; float f; } v; v.u = ((uint32_t)(uint16_t)s) << 16;
  return v.f;
}
__device__ __forceinline__ void g2l16(const void* g, void* l) {
  __builtin_amdgcn_global_load_lds((const __attribute__((address_space(1))) void*)g,
                                   (__attribute__((address_space(3))) void*)l, 16, 0, 0);
}

// ---------------- transpose + f32->bf16 convert -----------------------------
__global__ __launch_bounds__(256) void k_transpose_wf(const float* __restrict__ src,
                                                      short* __restrict__ dst) {
  __shared__ short tile[32][33];
  int c0 = blockIdx.x * 32;
  int r0 = blockIdx.y * 32;
  int tx = threadIdx.x & 31, ty = threadIdx.x >> 5;
#pragma unroll
  for (int i = 0; i < 32; i += 8)
    tile[ty + i][tx] = f2bf(src[(size_t)(r0 + ty + i) * FUSED + c0 + tx]);
  __syncthreads();
#pragma unroll
  for (int i = 0; i < 32; i += 8)
    dst[(size_t)(c0 + ty + i) * DIM + r0 + tx] = tile[tx][ty + i];
}

__global__ __launch_bounds__(256) void k_transpose_w2(const float* __restrict__ wao,
                                                      const float* __restrict__ wfo,
                                                      short* __restrict__ dst) {
  __shared__ short tile[32][33];
  int c0 = blockIdx.x * 32;
  int r0 = blockIdx.y * 32;
  int tx = threadIdx.x & 31, ty = threadIdx.x >> 5;
#pragma unroll
  for (int i = 0; i < 32; i += 8) {
    int r = r0 + ty + i;
    float v = (r < AINNER) ? wao[(size_t)r * DIM + c0 + tx]
                           : wfo[(size_t)(r - AINNER) * DIM + c0 + tx];
    tile[ty + i][tx] = f2bf(v);
  }
  __syncthreads();
#pragma unroll
  for (int i = 0; i < 32; i += 8)
    dst[(size_t)(c0 + ty + i) * HCOLS + r0 + tx] = tile[tx][ty + i];
}

// ---------------- layernorm -------------------------------------------------
__global__ __launch_bounds__(256) void k_ln(const float* __restrict__ x,
                                            const float* __restrict__ gamma,
                                            short* __restrict__ xn) {
  int row = blockIdx.x;
  int t = threadIdx.x;
  const float4* xr = (const float4*)(x + (size_t)row * DIM);
  float4 v = xr[t];
  float s = v.x + v.y + v.z + v.w;
  float s2 = v.x * v.x + v.y * v.y + v.z * v.z + v.w * v.w;
#pragma unroll
  for (int m = 1; m < 64; m <<= 1) { s += __shfl_xor(s, m); s2 += __shfl_xor(s2, m); }
  __shared__ float red[8];
  int w = t >> 6;
  if ((t & 63) == 0) { red[w] = s; red[4 + w] = s2; }
  __syncthreads();
  s = red[0] + red[1] + red[2] + red[3];
  s2 = red[4] + red[5] + red[6] + red[7];
  float mu = s * (1.f / DIM);
  float rs = rsqrtf(s2 * (1.f / DIM) - mu * mu + 1e-5f);
  const float4* g4 = (const float4*)gamma;
  float4 g = g4[t];
  short4v o;
  o.x = f2bf((v.x - mu) * rs * g.x);
  o.y = f2bf((v.y - mu) * rs * g.y);
  o.z = f2bf((v.z - mu) * rs * g.z);
  o.w = f2bf((v.w - mu) * rs * g.w);
  ((short4v*)(xn + (size_t)row * DIM))[t] = o;
}

// ---------------- 256xBN single-barrier dbuf GEMM ---------------------------
// 512 thr = 8 waves (2M x 4N). Wave tile 128 x BN/4. BK=64.
// Per K-tile: {vmcnt(0); barrier; issue ALL stages(kt+1 -> other buf);
//              ds_reads; MFMA}. One barrier/tile; full-tile drain slack.
// LDS (shorts): A (db*2+half)*8192 [32768 total]; B 32768 + (db*2+half)*BHALF.
// MODE 0 (BN=128): qkv+ffx split write; MODE 1 (BN=256): H = silu(gate)*H.
template <int MODE, int BN>
__global__ __launch_bounds__(512, 2) void gemm8(const short* __restrict__ A, int lda,
                                                const short* __restrict__ Bt, int ldb,
                                                int K, void* __restrict__ out0,
                                                void* __restrict__ out1,
                                                void* __restrict__ out2,
                                                void* __restrict__ out3) {
  extern __shared__ __align__(16) short S[];
  constexpr int NFR = BN / 64;             // B frags per wave (4 or 2)
  constexpr int BHALF = (BN == 256) ? 8192 : 4096;  // shorts per B half
  int tid = threadIdx.x, l = tid & 63, w = tid >> 6;
  int wm = w >> 2, wn = w & 3;
  int gx = gridDim.x, nwg = gx * gridDim.y;
  int hw = blockIdx.y * gx + blockIdx.x;
  int qq = nwg >> 3;                       // grids divisible by 8
  int tile = (hw & 7) * qq + (hw >> 3);    // XCD-contiguous remap
  int bx = tile % gx, by = tile / gx;
  int mBase = by * 256, nBase = bx * BN;

  int srow = w * 8 + (l >> 3);
  int cs = (l & 7) ^ (l >> 3);
  const short* Ag = A + (size_t)(mBase + srow) * lda + cs * 8;
  const short* Bg = Bt + (size_t)(nBase + srow) * ldb + cs * 8;
  int dsto = w * 512 + l * 8;

#define STAGE_ALL(kt, db2)                                                      \
  {                                                                             \
    _Pragma("unroll") for (int h = 0; h < 2; ++h)                               \
        _Pragma("unroll") for (int s2 = 0; s2 < 2; ++s2)                        \
            g2l16(Ag + (size_t)(h * 128 + s2 * 64) * lda + (kt) * 64,           \
                  S + ((db2) * 2 + h) * 8192 + s2 * 4096 + dsto);               \
    if constexpr (BN == 256) {                                                  \
      _Pragma("unroll") for (int h = 0; h < 2; ++h)                             \
          _Pragma("unroll") for (int s2 = 0; s2 < 2; ++s2)                      \
              g2l16(Bg + (size_t)(h * 128 + s2 * 64) * ldb + (kt) * 64,         \
                    S + 32768 + ((db2) * 2 + h) * 8192 + s2 * 4096 + dsto);     \
    } else {                                                                    \
      _Pragma("unroll") for (int h = 0; h < 2; ++h)                             \
          g2l16(Bg + (size_t)(h * 64) * ldb + (kt) * 64,                        \
                S + 32768 + ((db2) * 2 + h) * 4096 + dsto);                     \
    }                                                                           \
  }

  int NT = K >> 6;
  STAGE_ALL(0, 0);

  int c0 = l & 15, kg = l >> 4, cx = l & 7;
  int brow = (wn & 1) * (BN / 4);          // B row base within its half
  f32x4 zero = {0.f, 0.f, 0.f, 0.f};
  f32x4 acc[8][NFR];
#pragma unroll
  for (int m = 0; m < 8; ++m)
#pragma unroll
    for (int n = 0; n < NFR; ++n) acc[m][n] = zero;

  for (int kt = 0; kt < NT; ++kt) {
    int db = kt & 1, dbn = db ^ 1;
    // tile kt resident (loads had a full tile of slack); prev reads of dbn done
    asm volatile("s_waitcnt vmcnt(0)\ns_barrier" ::: "memory");
    if (kt + 1 < NT) STAGE_ALL(kt + 1, dbn);
    const short* Ab = S + (db * 2 + wm) * 8192;
    const short* Bb = S + 32768 + (db * 2 + (wn >> 1)) * BHALF;
#pragma unroll
    for (int kkh = 0; kkh < 2; ++kkh) {
      int ch = (kkh * 4 + kg) ^ cx;
      short8 b[NFR], a[8];
#pragma unroll
      for (int n = 0; n < NFR; ++n)
        b[n] = *(const short8*)(Bb + (brow + n * 16 + c0) * 64 + ch * 8);
#pragma unroll
      for (int m = 0; m < 8; ++m)
        a[m] = *(const short8*)(Ab + (m * 16 + c0) * 64 + ch * 8);
      __builtin_amdgcn_s_setprio(1);
#pragma unroll
      for (int m = 0; m < 8; ++m)
#pragma unroll
        for (int n = 0; n < NFR; ++n)
          acc[m][n] = __builtin_amdgcn_mfma_f32_16x16x32_bf16(a[m], b[n], acc[m][n], 0, 0, 0);
      __builtin_amdgcn_s_setprio(0);
    }
  }
#undef STAGE_ALL

  int r0 = (l >> 4) * 4;
#pragma unroll
  for (int m = 0; m < 8; ++m)
#pragma unroll
    for (int n = 0; n < NFR; ++n)
#pragma unroll
      for (int r = 0; r < 4; ++r) {
        float val = acc[m][n][r];
        int row = mBase + wm * 128 + m * 16 + r0 + r;
        int col = nBase + wn * (BN / 4) + n * 16 + c0;
        if (MODE == 0) {
          if (col < AINNER)
            ((short*)out0)[(size_t)row * AINNER + col] = f2bf(val);
          else if (col < AINNER + DH)
            ((short*)out1)[(size_t)row * DH + (col - AINNER)] = f2bf(val);
          else if (col < AINNER + 2 * DH)
            ((short*)out2)[((size_t)(row >> 11) * DH + (col - AINNER - DH)) * SEQ +
                           (row & (SEQ - 1))] = f2bf(val);
          else
            ((short*)out3)[(size_t)row * HCOLS + AINNER + (col - 640)] = f2bf(val);
        } else {
          short* Hp = (short*)out0;
          size_t idx = (size_t)row * HCOLS + AINNER + col;
          float sg = val / (1.f + __expf(-val));
          Hp[idx] = f2bf(sg * bf2f(Hp[idx]));
        }
      }
}

// ---------------- ring-4 counted-vmcnt 128x128 GEMM (f32 out, unchanged) ----
__global__ __launch_bounds__(512, 2) void gemm_r(const short* __restrict__ A, int lda,
                                                 const short* __restrict__ Bt, int ldb,
                                                 int K, float* __restrict__ out0) {
  extern __shared__ __align__(16) short SA[];
  int tid = threadIdx.x, l = tid & 63, w = tid >> 6;
  int gx = gridDim.x;
  int nwg = gx * gridDim.y;
  int hw = blockIdx.y * gx + blockIdx.x;
  int qq = nwg >> 3;
  int tile = (hw & 7) * qq + (hw >> 3);
  int bx = tile % gx, by = tile / gx;
  int mBase = by * 128, nBase = bx * 128;

  int srow = w * 8 + (l >> 3);
  int cs = (l & 7) ^ (l >> 3);
  const short* Ag = A + (size_t)(mBase + srow) * lda + cs * 8;
  const short* Bg = Bt + (size_t)(nBase + srow) * ldb + cs * 8;
  short* ldsA = SA + w * 512 + l * 8;
  short* ldsB = ldsA + 8192;

  int NT = K >> 6;
  for (int tt = 0; tt < 3; ++tt) {
    int slot = tt & 3;
#pragma unroll
    for (int i = 0; i < 2; ++i) {
      g2l16(Ag + (size_t)(i * 64) * lda + tt * 64, ldsA + slot * 16384 + i * 4096);
      g2l16(Bg + (size_t)(i * 64) * ldb + tt * 64, ldsB + slot * 16384 + i * 4096);
    }
  }

  int wr = w >> 2, wc = w & 3;
  int c0 = l & 15, kg = l >> 4, cx = l & 7;
  f32x4 zero = {0.f, 0.f, 0.f, 0.f};
  f32x4 acc[4][2];
#pragma unroll
  for (int m = 0; m < 4; ++m)
#pragma unroll
    for (int n = 0; n < 2; ++n) acc[m][n] = zero;

  for (int kt = 0; kt < NT; ++kt) {
    if (kt + 2 < NT)      asm volatile("s_waitcnt vmcnt(8)\ns_barrier" ::: "memory");
    else if (kt + 1 < NT) asm volatile("s_waitcnt vmcnt(4)\ns_barrier" ::: "memory");
    else                  asm volatile("s_waitcnt vmcnt(0)\ns_barrier" ::: "memory");
    int slot = kt & 3;
    const short* Ab = SA + slot * 16384;
    const short* Bb = Ab + 8192;
    short8 af[4][2], bfr[2][2];
#pragma unroll
    for (int m = 0; m < 4; ++m)
#pragma unroll
      for (int kk = 0; kk < 2; ++kk)
        af[m][kk] = *(const short8*)(Ab + (wr * 64 + m * 16 + c0) * 64 + ((kk * 4 + kg) ^ cx) * 8);
#pragma unroll
    for (int n = 0; n < 2; ++n)
#pragma unroll
      for (int kk = 0; kk < 2; ++kk)
        bfr[n][kk] = *(const short8*)(Bb + (wc * 32 + n * 16 + c0) * 64 + ((kk * 4 + kg) ^ cx) * 8);
    int ts = kt + 3;
    if (ts < NT) {
      int s2 = ts & 3;
#pragma unroll
      for (int i = 0; i < 2; ++i) {
        g2l16(Ag + (size_t)(i * 64) * lda + ts * 64, ldsA + s2 * 16384 + i * 4096);
        g2l16(Bg + (size_t)(i * 64) * ldb + ts * 64, ldsB + s2 * 16384 + i * 4096);
      }
    }
    __builtin_amdgcn_s_setprio(1);
#pragma unroll
    for (int m = 0; m < 4; ++m)
#pragma unroll
      for (int n = 0; n < 2; ++n)
#pragma unroll
        for (int kk = 0; kk < 2; ++kk)
          acc[m][n] = __builtin_amdgcn_mfma_f32_16x16x32_bf16(af[m][kk], bfr[n][kk],
                                                              acc[m][n], 0, 0, 0);
    __builtin_amdgcn_s_setprio(0);
  }

  int r0 = (l >> 4) * 4;
#pragma unroll
  for (int m = 0; m < 4; ++m)
#pragma unroll
    for (int n = 0; n < 2; ++n)
#pragma unroll
      for (int r = 0; r < 4; ++r) {
        int row = mBase + wr * 64 + m * 16 + r0 + r;
        int col = nBase + wc * 32 + n * 16 + c0;
        out0[(size_t)row * DIM + col] = acc[m][n][r];
      }
}

// ---------------- flash attention (unchanged) -------------------------------
__global__ __launch_bounds__(256) void k_attn(const short* __restrict__ qb,
                                              const short* __restrict__ kb,
                                              const short* __restrict__ vt,
                                              short* __restrict__ H) {
  __shared__ __align__(16) short Qs[64 * 64];
  __shared__ __align__(16) short Ks[128 * 64];
  __shared__ __align__(16) short Vs[64 * 128];
  __shared__ __align__(16) short Ps[4][16 * 128];
  int t = threadIdx.x, l = t & 63, w = t >> 6;
  int qt = blockIdx.x, bh = blockIdx.y;
  int b = bh >> 3, h = bh & 7;
  int q0 = qt * 64;

  int srow = w * 8 + (l >> 3);
  int schunk = (l & 7) ^ (l >> 3);
  {
    const short* Qg = qb + (size_t)(b * SEQ + q0 + srow) * AINNER + h * DH + schunk * 8;
    short* qs = Qs + w * 512 + l * 8;
#pragma unroll
    for (int i = 0; i < 2; ++i) g2l16(Qg + (size_t)(i * 32) * AINNER, qs + i * 2048);
  }
  const short* Kg = kb + (size_t)(b * SEQ + srow) * DH + schunk * 8;
  short* ksl = Ks + w * 512 + l * 8;
  int vrow = w * 4 + (l >> 4);
  int vchunk = (l & 15) ^ (vrow & 7);
  const short* Vg = vt + (size_t)b * DH * SEQ + (size_t)vrow * SEQ + vchunk * 8;
  short* vsl = Vs + w * 512 + l * 8;

#pragma unroll
  for (int i = 0; i < 4; ++i) {
    g2l16(Kg + (size_t)(i * 32) * DH, ksl + i * 2048);
    g2l16(Vg + (size_t)(i * 16) * SEQ, vsl + i * 2048);
  }

  float m_run[4], l_run[4];
  f32x4 zero = {0.f, 0.f, 0.f, 0.f};
  f32x4 Oacc[4];
#pragma unroll
  for (int r = 0; r < 4; ++r) { m_run[r] = -1e30f; l_run[r] = 0.f; }
#pragma unroll
  for (int n = 0; n < 4; ++n) Oacc[n] = zero;

  int c0 = l & 15, kg = l >> 4, cx = l & 7;
  short* pw = Ps[w];

  for (int kv0 = 0; kv0 < SEQ; kv0 += 128) {
    asm volatile("s_waitcnt vmcnt(0)\ns_barrier" ::: "memory");

    f32x4 sacc[8];
#pragma unroll
    for (int n = 0; n < 8; ++n) sacc[n] = zero;
#pragma unroll
    for (int kk = 0; kk < 2; ++kk) {
      int rr = w * 16 + c0;
      short8 aq = *(const short8*)(Qs + rr * 64 + ((kk * 4 + kg) ^ cx) * 8);
#pragma unroll
      for (int n = 0; n < 8; ++n) {
        int kr = n * 16 + c0;
        short8 bk = *(const short8*)(Ks + kr * 64 + ((kk * 4 + kg) ^ cx) * 8);
        sacc[n] = __builtin_amdgcn_mfma_f32_16x16x32_bf16(aq, bk, sacc[n], 0, 0, 0);
      }
    }
#pragma unroll
    for (int r = 0; r < 4; ++r) {
      float mx = -1e30f;
#pragma unroll
      for (int n = 0; n < 8; ++n) {
        sacc[n][r] *= 0.125f;
        mx = fmaxf(mx, sacc[n][r]);
      }
#pragma unroll
      for (int msk = 1; msk < 16; msk <<= 1) mx = fmaxf(mx, __shfl_xor(mx, msk));
      float nm = fmaxf(m_run[r], mx);
      float corr = __expf(m_run[r] - nm);
      m_run[r] = nm;
      float rs = 0.f;
#pragma unroll
      for (int n = 0; n < 8; ++n) {
        float p = __expf(sacc[n][r] - nm);
        sacc[n][r] = p;
        rs += p;
      }
#pragma unroll
      for (int msk = 1; msk < 16; msk <<= 1) rs += __shfl_xor(rs, msk);
      l_run[r] = l_run[r] * corr + rs;
      Oacc[0][r] *= corr; Oacc[1][r] *= corr; Oacc[2][r] *= corr; Oacc[3][r] *= corr;
    }
#pragma unroll
    for (int n = 0; n < 8; ++n)
#pragma unroll
      for (int r = 0; r < 4; ++r) {
        int pr = (l >> 4) * 4 + r;
        int pc = n * 16 + c0;
        pw[pr * 128 + ((pc >> 3) ^ (pr & 7)) * 8 + (pc & 7)] = f2bf(sacc[n][r]);
      }
    asm volatile("s_waitcnt lgkmcnt(0)" ::: "memory");
#pragma unroll
    for (int kk = 0; kk < 4; ++kk) {
      int pr = c0;
      short8 ap = *(const short8*)(pw + pr * 128 + ((kk * 4 + kg) ^ cx) * 8);
#pragma unroll
      for (int n = 0; n < 4; ++n) {
        int vr = n * 16 + c0;
        short8 bv = *(const short8*)(Vs + vr * 128 + ((kk * 4 + kg) ^ (vr & 7)) * 8);
        Oacc[n] = __builtin_amdgcn_mfma_f32_16x16x32_bf16(ap, bv, Oacc[n], 0, 0, 0);
      }
    }
    __syncthreads();
    int nx = kv0 + 128;
    if (nx < SEQ) {
#pragma unroll
      for (int i = 0; i < 4; ++i) {
        g2l16(Kg + (size_t)(nx + i * 32) * DH, ksl + i * 2048);
        g2l16(Vg + nx + (size_t)(i * 16) * SEQ, vsl + i * 2048);
      }
    }
  }
#pragma unroll
  for (int r = 0; r < 4; ++r) {
    float inv = 1.f / l_run[r];
    int row = b * SEQ + q0 + w * 16 + (l >> 4) * 4 + r;
#pragma unroll
    for (int n = 0; n < 4; ++n) {
      int col = h * DH + n * 16 + c0;
      H[(size_t)row * HCOLS + col] = f2bf(Oacc[n][r] * inv);
    }
  }
}

// ----------------------------------------------------------------------------
extern "C" void kernel_launch(void* const* d_in, const int* in_sizes, int n_in,
                              void* d_out, int out_size, void* d_ws, size_t ws_size,
                              hipStream_t stream) {
  const float* x     = (const float*)d_in[0];
  const float* gamma = (const float*)d_in[1];
  const float* w_f   = (const float*)d_in[2];
  const float* w_ao  = (const float*)d_in[3];
  const float* w_fo  = (const float*)d_in[4];
  float* out = (float*)d_out;

  char* ws = (char*)d_ws;
  size_t o = 0;
  short* WtF = (short*)(ws + o); o += (size_t)FUSED * DIM * 2;
  short* Wt2 = (short*)(ws + o); o += (size_t)DIM * HCOLS * 2;
  short* xn  = (short*)(ws + o); o += (size_t)NTOK * DIM * 2;
  short* qb  = (short*)(ws + o); o += (size_t)NTOK * AINNER * 2;
  short* kbf = (short*)(ws + o); o += (size_t)NTOK * DH * 2;
  short* vtb = (short*)(ws + o); o += (size_t)NTOK * DH * 2;
  short* H   = (short*)(ws + o); o += (size_t)NTOK * HCOLS * 2;

  k_transpose_wf<<<dim3(FUSED / 32, DIM / 32), 256, 0, stream>>>(w_f, WtF);
  k_transpose_w2<<<dim3(DIM / 32, HCOLS / 32), 256, 0, stream>>>(w_ao, w_fo, Wt2);
  k_ln<<<NTOK, 256, 0, stream>>>(x, gamma, xn);
  // q,k,v,ffx: fused cols 0..4735, BN=128: 37x16 = 592 blocks (no padding)
  gemm8<0, 128><<<dim3(37, 16), 512, 98304, stream>>>(xn, DIM, WtF, DIM, DIM,
                                                      qb, kbf, vtb, H);
  k_attn<<<dim3(32, 16), 256, 0, stream>>>(qb, kbf, vtb, H);
  // gate: fused cols 4736..8831, BN=256: 16x16 = 256 blocks
  gemm8<1, 256><<<dim3(16, 16), 512, 131072, stream>>>(xn, DIM, WtF + (size_t)4736 * DIM, DIM,
                                                       DIM, H, nullptr, nullptr, nullptr);
  // out = H (4096x4608) @ [w_attn_out; w_ff_out]
  gemm_r<<<dim3(8, 32), 512, 131072, stream>>>(H, HCOLS, Wt2, HCOLS, HCOLS, out);
}

// Round 8
// 223.372 us; speedup vs baseline: 1.2211x; 1.0380x over previous
//
#include <hip/hip_runtime.h>
#include <hip/hip_bf16.h>
#include <stdint.h>

#define DIM     1024
#define SEQ     2048
#define NTOK    4096
#define HEADS   8
#define DH      64
#define AINNER  512
#define FFI     4096
#define FUSED   8832
#define HCOLS   4608   // 512 attn-out cols + 4096 gated-ff cols

typedef __attribute__((ext_vector_type(8))) short short8;
typedef __attribute__((ext_vector_type(4))) short short4v;
typedef __attribute__((ext_vector_type(4))) float f32x4;

__device__ __forceinline__ short f2bf(float f) {
  union { float f; uint32_t u; } v; v.f = f;
  uint32_t r = v.u + 0x7fffu + ((v.u >> 16) & 1u);
  return (short)(r >> 16);
}
__device__ __forceinline__ float bf2f(short s) {
  union { uint32_t u; float f; } v; v.u = ((uint32_t)(uint16_t)s) << 16;
  return v.f;
}
__device__ __forceinline__ void g2l16(const void* g, void* l) {
  __builtin_amdgcn_global_load_lds((const __attribute__((address_space(1))) void*)g,
                                   (__attribute__((address_space(3))) void*)l, 16, 0, 0);
}

// ---------------- transpose + f32->bf16 convert -----------------------------
__global__ __launch_bounds__(256) void k_transpose_wf(const float* __restrict__ src,
                                                      short* __restrict__ dst) {
  __shared__ short tile[32][33];
  int c0 = blockIdx.x * 32;
  int r0 = blockIdx.y * 32;
  int tx = threadIdx.x & 31, ty = threadIdx.x >> 5;
#pragma unroll
  for (int i = 0; i < 32; i += 8)
    tile[ty + i][tx] = f2bf(src[(size_t)(r0 + ty + i) * FUSED + c0 + tx]);
  __syncthreads();
#pragma unroll
  for (int i = 0; i < 32; i += 8)
    dst[(size_t)(c0 + ty + i) * DIM + r0 + tx] = tile[tx][ty + i];
}

__global__ __launch_bounds__(256) void k_transpose_w2(const float* __restrict__ wao,
                                                      const float* __restrict__ wfo,
                                                      short* __restrict__ dst) {
  __shared__ short tile[32][33];
  int c0 = blockIdx.x * 32;
  int r0 = blockIdx.y * 32;
  int tx = threadIdx.x & 31, ty = threadIdx.x >> 5;
#pragma unroll
  for (int i = 0; i < 32; i += 8) {
    int r = r0 + ty + i;
    float v = (r < AINNER) ? wao[(size_t)r * DIM + c0 + tx]
                           : wfo[(size_t)(r - AINNER) * DIM + c0 + tx];
    tile[ty + i][tx] = f2bf(v);
  }
  __syncthreads();
#pragma unroll
  for (int i = 0; i < 32; i += 8)
    dst[(size_t)(c0 + ty + i) * HCOLS + r0 + tx] = tile[tx][ty + i];
}

// ---------------- layernorm -------------------------------------------------
__global__ __launch_bounds__(256) void k_ln(const float* __restrict__ x,
                                            const float* __restrict__ gamma,
                                            short* __restrict__ xn) {
  int row = blockIdx.x;
  int t = threadIdx.x;
  const float4* xr = (const float4*)(x + (size_t)row * DIM);
  float4 v = xr[t];
  float s = v.x + v.y + v.z + v.w;
  float s2 = v.x * v.x + v.y * v.y + v.z * v.z + v.w * v.w;
#pragma unroll
  for (int m = 1; m < 64; m <<= 1) { s += __shfl_xor(s, m); s2 += __shfl_xor(s2, m); }
  __shared__ float red[8];
  int w = t >> 6;
  if ((t & 63) == 0) { red[w] = s; red[4 + w] = s2; }
  __syncthreads();
  s = red[0] + red[1] + red[2] + red[3];
  s2 = red[4] + red[5] + red[6] + red[7];
  float mu = s * (1.f / DIM);
  float rs = rsqrtf(s2 * (1.f / DIM) - mu * mu + 1e-5f);
  const float4* g4 = (const float4*)gamma;
  float4 g = g4[t];
  short4v o;
  o.x = f2bf((v.x - mu) * rs * g.x);
  o.y = f2bf((v.y - mu) * rs * g.y);
  o.z = f2bf((v.z - mu) * rs * g.z);
  o.w = f2bf((v.w - mu) * rs * g.w);
  ((short4v*)(xn + (size_t)row * DIM))[t] = o;
}

// ---------------- p1: fused qkv + silu(gate)*ffx GEMM -----------------------
// grid (37,16), 512 thr = 8 waves (2M x 4N), 256-row tiles, BK=64, 128KB LDS.
// Blocks bx<32: dual B panels (ffx cols 640+bx*128, gate cols 4736+bx*128),
//   wave tile 128x32(ffx)+128x32(gate) -> H = silu(gate)*ffx in-register.
// Blocks bx>=32: single B panel (qkv cols (bx-32)*128) -> q/k/vT split write.
// Per K-tile: {vmcnt(0); barrier; stage(kt+1 -> other buf); reads+MFMA}.
__global__ __launch_bounds__(512, 2) void p1(const short* __restrict__ A,
                                             const short* __restrict__ Bt,
                                             short* __restrict__ qb,
                                             short* __restrict__ kbf,
                                             short* __restrict__ vtb,
                                             short* __restrict__ H) {
  extern __shared__ __align__(16) short S[];  // A: db*16384; B: 32768 + db*16384
  int tid = threadIdx.x, l = tid & 63, w = tid >> 6;
  int wm = w >> 2, wn = w & 3;
  int hw = blockIdx.y * 37 + blockIdx.x;      // 592 blocks, %8==0
  int tile = (hw & 7) * 74 + (hw >> 3);       // XCD-contiguous remap
  int bx = tile % 37, by = tile / 37;
  int mBase = by * 256;
  bool fused = bx < 32;
  int b0row = fused ? (640 + bx * 128) : ((bx - 32) * 128);
  int b1row = 4736 + bx * 128;                // gate panel (fused only)

  int srow = w * 8 + (l >> 3);
  int cs = (l & 7) ^ (l >> 3);
  const short* Ag = A + (size_t)(mBase + srow) * DIM + cs * 8;
  const short* Bg0 = Bt + (size_t)(b0row + srow) * DIM + cs * 8;
  const short* Bg1 = Bt + (size_t)(b1row + srow) * DIM + cs * 8;
  int dsto = w * 512 + l * 8;

#define P1_STAGE(kt, db)                                                        \
  {                                                                             \
    _Pragma("unroll") for (int i = 0; i < 4; ++i)                               \
        g2l16(Ag + (size_t)(i * 64) * DIM + (kt) * 64,                          \
              S + (db) * 16384 + i * 4096 + dsto);                              \
    _Pragma("unroll") for (int i = 0; i < 2; ++i)                               \
        g2l16(Bg0 + (size_t)(i * 64) * DIM + (kt) * 64,                         \
              S + 32768 + (db) * 16384 + i * 4096 + dsto);                      \
    if (fused) {                                                                \
      _Pragma("unroll") for (int i = 0; i < 2; ++i)                             \
          g2l16(Bg1 + (size_t)(i * 64) * DIM + (kt) * 64,                       \
                S + 32768 + (db) * 16384 + 8192 + i * 4096 + dsto);             \
    }                                                                           \
  }

  const int NT = DIM / 64;  // 16
  P1_STAGE(0, 0);

  int c0 = l & 15, kg = l >> 4, cx = l & 7;
  f32x4 zero = {0.f, 0.f, 0.f, 0.f};
  f32x4 accF[8][2], accG[8][2];
#pragma unroll
  for (int m = 0; m < 8; ++m)
#pragma unroll
    for (int n = 0; n < 2; ++n) { accF[m][n] = zero; accG[m][n] = zero; }

  for (int kt = 0; kt < NT; ++kt) {
    int db = kt & 1, dbn = db ^ 1;
    asm volatile("s_waitcnt vmcnt(0)\ns_barrier" ::: "memory");
    if (kt + 1 < NT) P1_STAGE(kt + 1, dbn);
    const short* Ab = S + db * 16384;
    const short* Bb = S + 32768 + db * 16384;
#pragma unroll
    for (int kkh = 0; kkh < 2; ++kkh) {
      int ch8 = ((kkh * 4 + kg) ^ cx) * 8;
      short8 bf0 = *(const short8*)(Bb + (wn * 32 + c0) * 64 + ch8);
      short8 bf1 = *(const short8*)(Bb + (wn * 32 + 16 + c0) * 64 + ch8);
      if (fused) {
        short8 bg0 = *(const short8*)(Bb + (128 + wn * 32 + c0) * 64 + ch8);
        short8 bg1 = *(const short8*)(Bb + (128 + wn * 32 + 16 + c0) * 64 + ch8);
        __builtin_amdgcn_s_setprio(1);
#pragma unroll
        for (int m = 0; m < 8; ++m) {
          short8 a = *(const short8*)(Ab + (wm * 128 + m * 16 + c0) * 64 + ch8);
          accF[m][0] = __builtin_amdgcn_mfma_f32_16x16x32_bf16(a, bf0, accF[m][0], 0, 0, 0);
          accF[m][1] = __builtin_amdgcn_mfma_f32_16x16x32_bf16(a, bf1, accF[m][1], 0, 0, 0);
          accG[m][0] = __builtin_amdgcn_mfma_f32_16x16x32_bf16(a, bg0, accG[m][0], 0, 0, 0);
          accG[m][1] = __builtin_amdgcn_mfma_f32_16x16x32_bf16(a, bg1, accG[m][1], 0, 0, 0);
        }
        __builtin_amdgcn_s_setprio(0);
      } else {
        __builtin_amdgcn_s_setprio(1);
#pragma unroll
        for (int m = 0; m < 8; ++m) {
          short8 a = *(const short8*)(Ab + (wm * 128 + m * 16 + c0) * 64 + ch8);
          accF[m][0] = __builtin_amdgcn_mfma_f32_16x16x32_bf16(a, bf0, accF[m][0], 0, 0, 0);
          accF[m][1] = __builtin_amdgcn_mfma_f32_16x16x32_bf16(a, bf1, accF[m][1], 0, 0, 0);
        }
        __builtin_amdgcn_s_setprio(0);
      }
    }
  }
#undef P1_STAGE

  int r0 = (l >> 4) * 4;
#pragma unroll
  for (int m = 0; m < 8; ++m)
#pragma unroll
    for (int n = 0; n < 2; ++n)
#pragma unroll
      for (int r = 0; r < 4; ++r) {
        int row = mBase + wm * 128 + m * 16 + r0 + r;
        if (fused) {
          int col = bx * 128 + wn * 32 + n * 16 + c0;     // 0..4095
          float g = accG[m][n][r];
          float sg = g / (1.f + __expf(-g));
          H[(size_t)row * HCOLS + AINNER + col] = f2bf(sg * accF[m][n][r]);
        } else {
          int col = (bx - 32) * 128 + wn * 32 + n * 16 + c0;  // 0..639
          float val = accF[m][n][r];
          if (col < AINNER)
            qb[(size_t)row * AINNER + col] = f2bf(val);
          else if (col < AINNER + DH)
            kbf[(size_t)row * DH + (col - AINNER)] = f2bf(val);
          else
            vtb[((size_t)(row >> 11) * DH + (col - AINNER - DH)) * SEQ +
                (row & (SEQ - 1))] = f2bf(val);
        }
      }
}

// ---------------- out-GEMM: 256x256 split-K=4, bf16 partials ----------------
// grid (4,16,4): bz = K-slice (K=1152, 18 tiles). Same loop structure as p1.
__global__ __launch_bounds__(512, 2) void gemm_s(const short* __restrict__ A,
                                                 const short* __restrict__ Bt,
                                                 short* __restrict__ part) {
  extern __shared__ __align__(16) short S[];
  int tid = threadIdx.x, l = tid & 63, w = tid >> 6;
  int wm = w >> 2, wn = w & 3;
  int hw = (blockIdx.z * 16 + blockIdx.y) * 4 + blockIdx.x;  // 256 blocks
  int tile = (hw & 7) * 32 + (hw >> 3);
  int bx = tile & 3, by = (tile >> 2) & 15, bz = tile >> 6;
  int mBase = by * 256, nBase = bx * 256;
  int kOff = bz * 1152;

  int srow = w * 8 + (l >> 3);
  int cs = (l & 7) ^ (l >> 3);
  const short* Ag = A + (size_t)(mBase + srow) * HCOLS + kOff + cs * 8;
  const short* Bg = Bt + (size_t)(nBase + srow) * HCOLS + kOff + cs * 8;
  int dsto = w * 512 + l * 8;

#define GS_STAGE(kt, db)                                                        \
  {                                                                             \
    _Pragma("unroll") for (int i = 0; i < 4; ++i) {                             \
      g2l16(Ag + (size_t)(i * 64) * HCOLS + (kt) * 64,                          \
            S + (db) * 16384 + i * 4096 + dsto);                                \
      g2l16(Bg + (size_t)(i * 64) * HCOLS + (kt) * 64,                          \
            S + 32768 + (db) * 16384 + i * 4096 + dsto);                        \
    }                                                                           \
  }

  const int NT = 18;
  GS_STAGE(0, 0);

  int c0 = l & 15, kg = l >> 4, cx = l & 7;
  f32x4 zero = {0.f, 0.f, 0.f, 0.f};
  f32x4 acc[8][4];
#pragma unroll
  for (int m = 0; m < 8; ++m)
#pragma unroll
    for (int n = 0; n < 4; ++n) acc[m][n] = zero;

  for (int kt = 0; kt < NT; ++kt) {
    int db = kt & 1, dbn = db ^ 1;
    asm volatile("s_waitcnt vmcnt(0)\ns_barrier" ::: "memory");
    if (kt + 1 < NT) GS_STAGE(kt + 1, dbn);
    const short* Ab = S + db * 16384;
    const short* Bb = S + 32768 + db * 16384;
#pragma unroll
    for (int kkh = 0; kkh < 2; ++kkh) {
      int ch8 = ((kkh * 4 + kg) ^ cx) * 8;
      short8 b[4];
#pragma unroll
      for (int n = 0; n < 4; ++n)
        b[n] = *(const short8*)(Bb + (wn * 64 + n * 16 + c0) * 64 + ch8);
      __builtin_amdgcn_s_setprio(1);
#pragma unroll
      for (int m = 0; m < 8; ++m) {
        short8 a = *(const short8*)(Ab + (wm * 128 + m * 16 + c0) * 64 + ch8);
#pragma unroll
        for (int n = 0; n < 4; ++n)
          acc[m][n] = __builtin_amdgcn_mfma_f32_16x16x32_bf16(a, b[n], acc[m][n], 0, 0, 0);
      }
      __builtin_amdgcn_s_setprio(0);
    }
  }
#undef GS_STAGE

  int r0 = (l >> 4) * 4;
#pragma unroll
  for (int m = 0; m < 8; ++m)
#pragma unroll
    for (int n = 0; n < 4; ++n)
#pragma unroll
      for (int r = 0; r < 4; ++r) {
        int row = mBase + wm * 128 + m * 16 + r0 + r;
        int col = nBase + wn * 64 + n * 16 + c0;
        part[(size_t)bz * (NTOK * DIM) + (size_t)row * DIM + col] = f2bf(acc[m][n][r]);
      }
}

__global__ __launch_bounds__(256) void k_red(const short* __restrict__ part,
                                             float* __restrict__ out) {
  int i = (blockIdx.x * 256 + threadIdx.x) * 4;
  float4 s = {0.f, 0.f, 0.f, 0.f};
#pragma unroll
  for (int ks = 0; ks < 4; ++ks) {
    short4v v = *(const short4v*)(part + (size_t)ks * (NTOK * DIM) + i);
    s.x += bf2f(v.x); s.y += bf2f(v.y); s.z += bf2f(v.z); s.w += bf2f(v.w);
  }
  *(float4*)(out + i) = s;
}

// ---------------- ring-4 counted-vmcnt 128x128 GEMM (fallback) --------------
__global__ __launch_bounds__(512, 2) void gemm_r(const short* __restrict__ A, int lda,
                                                 const short* __restrict__ Bt, int ldb,
                                                 int K, float* __restrict__ out0) {
  extern __shared__ __align__(16) short SA[];
  int tid = threadIdx.x, l = tid & 63, w = tid >> 6;
  int gx = gridDim.x;
  int nwg = gx * gridDim.y;
  int hw = blockIdx.y * gx + blockIdx.x;
  int qq = nwg >> 3;
  int tile = (hw & 7) * qq + (hw >> 3);
  int bx = tile % gx, by = tile / gx;
  int mBase = by * 128, nBase = bx * 128;

  int srow = w * 8 + (l >> 3);
  int cs = (l & 7) ^ (l >> 3);
  const short* Ag = A + (size_t)(mBase + srow) * lda + cs * 8;
  const short* Bg = Bt + (size_t)(nBase + srow) * ldb + cs * 8;
  short* ldsA = SA + w * 512 + l * 8;
  short* ldsB = ldsA + 8192;

  int NT = K >> 6;
  for (int tt = 0; tt < 3; ++tt) {
    int slot = tt & 3;
#pragma unroll
    for (int i = 0; i < 2; ++i) {
      g2l16(Ag + (size_t)(i * 64) * lda + tt * 64, ldsA + slot * 16384 + i * 4096);
      g2l16(Bg + (size_t)(i * 64) * ldb + tt * 64, ldsB + slot * 16384 + i * 4096);
    }
  }

  int wr = w >> 2, wc = w & 3;
  int c0 = l & 15, kg = l >> 4, cx = l & 7;
  f32x4 zero = {0.f, 0.f, 0.f, 0.f};
  f32x4 acc[4][2];
#pragma unroll
  for (int m = 0; m < 4; ++m)
#pragma unroll
    for (int n = 0; n < 2; ++n) acc[m][n] = zero;

  for (int kt = 0; kt < NT; ++kt) {
    if (kt + 2 < NT)      asm volatile("s_waitcnt vmcnt(8)\ns_barrier" ::: "memory");
    else if (kt + 1 < NT) asm volatile("s_waitcnt vmcnt(4)\ns_barrier" ::: "memory");
    else                  asm volatile("s_waitcnt vmcnt(0)\ns_barrier" ::: "memory");
    int slot = kt & 3;
    const short* Ab = SA + slot * 16384;
    const short* Bb = Ab + 8192;
    short8 af[4][2], bfr[2][2];
#pragma unroll
    for (int m = 0; m < 4; ++m)
#pragma unroll
      for (int kk = 0; kk < 2; ++kk)
        af[m][kk] = *(const short8*)(Ab + (wr * 64 + m * 16 + c0) * 64 + ((kk * 4 + kg) ^ cx) * 8);
#pragma unroll
    for (int n = 0; n < 2; ++n)
#pragma unroll
      for (int kk = 0; kk < 2; ++kk)
        bfr[n][kk] = *(const short8*)(Bb + (wc * 32 + n * 16 + c0) * 64 + ((kk * 4 + kg) ^ cx) * 8);
    int ts = kt + 3;
    if (ts < NT) {
      int s2 = ts & 3;
#pragma unroll
      for (int i = 0; i < 2; ++i) {
        g2l16(Ag + (size_t)(i * 64) * lda + ts * 64, ldsA + s2 * 16384 + i * 4096);
        g2l16(Bg + (size_t)(i * 64) * ldb + ts * 64, ldsB + s2 * 16384 + i * 4096);
      }
    }
    __builtin_amdgcn_s_setprio(1);
#pragma unroll
    for (int m = 0; m < 4; ++m)
#pragma unroll
      for (int n = 0; n < 2; ++n)
#pragma unroll
        for (int kk = 0; kk < 2; ++kk)
          acc[m][n] = __builtin_amdgcn_mfma_f32_16x16x32_bf16(af[m][kk], bfr[n][kk],
                                                              acc[m][n], 0, 0, 0);
    __builtin_amdgcn_s_setprio(0);
  }

  int r0 = (l >> 4) * 4;
#pragma unroll
  for (int m = 0; m < 4; ++m)
#pragma unroll
    for (int n = 0; n < 2; ++n)
#pragma unroll
      for (int r = 0; r < 4; ++r) {
        int row = mBase + wr * 64 + m * 16 + r0 + r;
        int col = nBase + wc * 32 + n * 16 + c0;
        out0[(size_t)row * DIM + col] = acc[m][n][r];
      }
}

// ---------------- flash attention (unchanged) -------------------------------
__global__ __launch_bounds__(256) void k_attn(const short* __restrict__ qb,
                                              const short* __restrict__ kb,
                                              const short* __restrict__ vt,
                                              short* __restrict__ H) {
  __shared__ __align__(16) short Qs[64 * 64];
  __shared__ __align__(16) short Ks[128 * 64];
  __shared__ __align__(16) short Vs[64 * 128];
  __shared__ __align__(16) short Ps[4][16 * 128];
  int t = threadIdx.x, l = t & 63, w = t >> 6;
  int qt = blockIdx.x, bh = blockIdx.y;
  int b = bh >> 3, h = bh & 7;
  int q0 = qt * 64;

  int srow = w * 8 + (l >> 3);
  int schunk = (l & 7) ^ (l >> 3);
  {
    const short* Qg = qb + (size_t)(b * SEQ + q0 + srow) * AINNER + h * DH + schunk * 8;
    short* qs = Qs + w * 512 + l * 8;
#pragma unroll
    for (int i = 0; i < 2; ++i) g2l16(Qg + (size_t)(i * 32) * AINNER, qs + i * 2048);
  }
  const short* Kg = kb + (size_t)(b * SEQ + srow) * DH + schunk * 8;
  short* ksl = Ks + w * 512 + l * 8;
  int vrow = w * 4 + (l >> 4);
  int vchunk = (l & 15) ^ (vrow & 7);
  const short* Vg = vt + (size_t)b * DH * SEQ + (size_t)vrow * SEQ + vchunk * 8;
  short* vsl = Vs + w * 512 + l * 8;

#pragma unroll
  for (int i = 0; i < 4; ++i) {
    g2l16(Kg + (size_t)(i * 32) * DH, ksl + i * 2048);
    g2l16(Vg + (size_t)(i * 16) * SEQ, vsl + i * 2048);
  }

  float m_run[4], l_run[4];
  f32x4 zero = {0.f, 0.f, 0.f, 0.f};
  f32x4 Oacc[4];
#pragma unroll
  for (int r = 0; r < 4; ++r) { m_run[r] = -1e30f; l_run[r] = 0.f; }
#pragma unroll
  for (int n = 0; n < 4; ++n) Oacc[n] = zero;

  int c0 = l & 15, kg = l >> 4, cx = l & 7;
  short* pw = Ps[w];

  for (int kv0 = 0; kv0 < SEQ; kv0 += 128) {
    asm volatile("s_waitcnt vmcnt(0)\ns_barrier" ::: "memory");

    f32x4 sacc[8];
#pragma unroll
    for (int n = 0; n < 8; ++n) sacc[n] = zero;
#pragma unroll
    for (int kk = 0; kk < 2; ++kk) {
      int rr = w * 16 + c0;
      short8 aq = *(const short8*)(Qs + rr * 64 + ((kk * 4 + kg) ^ cx) * 8);
#pragma unroll
      for (int n = 0; n < 8; ++n) {
        int kr = n * 16 + c0;
        short8 bk = *(const short8*)(Ks + kr * 64 + ((kk * 4 + kg) ^ cx) * 8);
        sacc[n] = __builtin_amdgcn_mfma_f32_16x16x32_bf16(aq, bk, sacc[n], 0, 0, 0);
      }
    }
#pragma unroll
    for (int r = 0; r < 4; ++r) {
      float mx = -1e30f;
#pragma unroll
      for (int n = 0; n < 8; ++n) {
        sacc[n][r] *= 0.125f;
        mx = fmaxf(mx, sacc[n][r]);
      }
#pragma unroll
      for (int msk = 1; msk < 16; msk <<= 1) mx = fmaxf(mx, __shfl_xor(mx, msk));
      float nm = fmaxf(m_run[r], mx);
      float corr = __expf(m_run[r] - nm);
      m_run[r] = nm;
      float rs = 0.f;
#pragma unroll
      for (int n = 0; n < 8; ++n) {
        float p = __expf(sacc[n][r] - nm);
        sacc[n][r] = p;
        rs += p;
      }
#pragma unroll
      for (int msk = 1; msk < 16; msk <<= 1) rs += __shfl_xor(rs, msk);
      l_run[r] = l_run[r] * corr + rs;
      Oacc[0][r] *= corr; Oacc[1][r] *= corr; Oacc[2][r] *= corr; Oacc[3][r] *= corr;
    }
#pragma unroll
    for (int n = 0; n < 8; ++n)
#pragma unroll
      for (int r = 0; r < 4; ++r) {
        int pr = (l >> 4) * 4 + r;
        int pc = n * 16 + c0;
        pw[pr * 128 + ((pc >> 3) ^ (pr & 7)) * 8 + (pc & 7)] = f2bf(sacc[n][r]);
      }
    asm volatile("s_waitcnt lgkmcnt(0)" ::: "memory");
#pragma unroll
    for (int kk = 0; kk < 4; ++kk) {
      int pr = c0;
      short8 ap = *(const short8*)(pw + pr * 128 + ((kk * 4 + kg) ^ cx) * 8);
#pragma unroll
      for (int n = 0; n < 4; ++n) {
        int vr = n * 16 + c0;
        short8 bv = *(const short8*)(Vs + vr * 128 + ((kk * 4 + kg) ^ (vr & 7)) * 8);
        Oacc[n] = __builtin_amdgcn_mfma_f32_16x16x32_bf16(ap, bv, Oacc[n], 0, 0, 0);
      }
    }
    __syncthreads();
    int nx = kv0 + 128;
    if (nx < SEQ) {
#pragma unroll
      for (int i = 0; i < 4; ++i) {
        g2l16(Kg + (size_t)(nx + i * 32) * DH, ksl + i * 2048);
        g2l16(Vg + nx + (size_t)(i * 16) * SEQ, vsl + i * 2048);
      }
    }
  }
#pragma unroll
  for (int r = 0; r < 4; ++r) {
    float inv = 1.f / l_run[r];
    int row = b * SEQ + q0 + w * 16 + (l >> 4) * 4 + r;
#pragma unroll
    for (int n = 0; n < 4; ++n) {
      int col = h * DH + n * 16 + c0;
      H[(size_t)row * HCOLS + col] = f2bf(Oacc[n][r] * inv);
    }
  }
}

// ----------------------------------------------------------------------------
extern "C" void kernel_launch(void* const* d_in, const int* in_sizes, int n_in,
                              void* d_out, int out_size, void* d_ws, size_t ws_size,
                              hipStream_t stream) {
  const float* x     = (const float*)d_in[0];
  const float* gamma = (const float*)d_in[1];
  const float* w_f   = (const float*)d_in[2];
  const float* w_ao  = (const float*)d_in[3];
  const float* w_fo  = (const float*)d_in[4];
  float* out = (float*)d_out;

  char* ws = (char*)d_ws;
  size_t o = 0;
  short* WtF = (short*)(ws + o); o += (size_t)FUSED * DIM * 2;
  short* Wt2 = (short*)(ws + o); o += (size_t)DIM * HCOLS * 2;
  short* xn  = (short*)(ws + o); o += (size_t)NTOK * DIM * 2;
  short* qb  = (short*)(ws + o); o += (size_t)NTOK * AINNER * 2;
  short* kbf = (short*)(ws + o); o += (size_t)NTOK * DH * 2;
  short* vtb = (short*)(ws + o); o += (size_t)NTOK * DH * 2;
  short* H   = (short*)(ws + o); o += (size_t)NTOK * HCOLS * 2;
  short* part = (short*)(ws + o);
  size_t need = o + (size_t)4 * NTOK * DIM * 2;   // +33.5 MB for split-K partials

  k_transpose_wf<<<dim3(FUSED / 32, DIM / 32), 256, 0, stream>>>(w_f, WtF);
  k_transpose_w2<<<dim3(DIM / 32, HCOLS / 32), 256, 0, stream>>>(w_ao, w_fo, Wt2);
  k_ln<<<NTOK, 256, 0, stream>>>(x, gamma, xn);
  // qkv + H=silu(gate)*ffx in one dispatch
  p1<<<dim3(37, 16), 512, 131072, stream>>>(xn, WtF, qb, kbf, vtb, H);
  k_attn<<<dim3(32, 16), 256, 0, stream>>>(qb, kbf, vtb, H);
  // out = H (4096x4608) @ [w_attn_out; w_ff_out]
  if (ws_size >= need) {
    gemm_s<<<dim3(4, 16, 4), 512, 131072, stream>>>(H, Wt2, part);
    k_red<<<NTOK * DIM / 1024, 256, 0, stream>>>(part, out);
  } else {
    gemm_r<<<dim3(8, 32), 512, 131072, stream>>>(H, HCOLS, Wt2, HCOLS, HCOLS, out);
  }
}

// Round 9
// 211.680 us; speedup vs baseline: 1.2886x; 1.0552x over previous
//
#include <hip/hip_runtime.h>
#include <hip/hip_bf16.h>
#include <stdint.h>

#define DIM     1024
#define SEQ     2048
#define NTOK    4096
#define HEADS   8
#define DH      64
#define AINNER  512
#define FFI     4096
#define FUSED   8832
#define HCOLS   4608   // 512 attn-out cols + 4096 gated-ff cols

typedef __attribute__((ext_vector_type(8))) short short8;
typedef __attribute__((ext_vector_type(4))) short short4v;
typedef __attribute__((ext_vector_type(4))) float f32x4;

__device__ __forceinline__ short f2bf(float f) {
  union { float f; uint32_t u; } v; v.f = f;
  uint32_t r = v.u + 0x7fffu + ((v.u >> 16) & 1u);
  return (short)(r >> 16);
}
__device__ __forceinline__ float bf2f(short s) {
  union { uint32_t u; float f; } v; v.u = ((uint32_t)(uint16_t)s) << 16;
  return v.f;
}
__device__ __forceinline__ void g2l16(const void* g, void* l) {
  __builtin_amdgcn_global_load_lds((const __attribute__((address_space(1))) void*)g,
                                   (__attribute__((address_space(3))) void*)l, 16, 0, 0);
}

#define PH_W4 asm volatile("s_waitcnt vmcnt(4)\ns_barrier" ::: "memory")
#define PH_W2 asm volatile("s_waitcnt vmcnt(2)\ns_barrier" ::: "memory")
#define PH_W0 asm volatile("s_waitcnt vmcnt(0)\ns_barrier" ::: "memory")
#define PH_B  asm volatile("s_barrier" ::: "memory")

// ---------------- transpose + f32->bf16 convert -----------------------------
__global__ __launch_bounds__(256) void k_transpose_wf(const float* __restrict__ src,
                                                      short* __restrict__ dst) {
  __shared__ short tile[32][33];
  int c0 = blockIdx.x * 32;
  int r0 = blockIdx.y * 32;
  int tx = threadIdx.x & 31, ty = threadIdx.x >> 5;
#pragma unroll
  for (int i = 0; i < 32; i += 8)
    tile[ty + i][tx] = f2bf(src[(size_t)(r0 + ty + i) * FUSED + c0 + tx]);
  __syncthreads();
#pragma unroll
  for (int i = 0; i < 32; i += 8)
    dst[(size_t)(c0 + ty + i) * DIM + r0 + tx] = tile[tx][ty + i];
}

__global__ __launch_bounds__(256) void k_transpose_w2(const float* __restrict__ wao,
                                                      const float* __restrict__ wfo,
                                                      short* __restrict__ dst) {
  __shared__ short tile[32][33];
  int c0 = blockIdx.x * 32;
  int r0 = blockIdx.y * 32;
  int tx = threadIdx.x & 31, ty = threadIdx.x >> 5;
#pragma unroll
  for (int i = 0; i < 32; i += 8) {
    int r = r0 + ty + i;
    float v = (r < AINNER) ? wao[(size_t)r * DIM + c0 + tx]
                           : wfo[(size_t)(r - AINNER) * DIM + c0 + tx];
    tile[ty + i][tx] = f2bf(v);
  }
  __syncthreads();
#pragma unroll
  for (int i = 0; i < 32; i += 8)
    dst[(size_t)(c0 + ty + i) * HCOLS + r0 + tx] = tile[tx][ty + i];
}

// ---------------- layernorm -------------------------------------------------
__global__ __launch_bounds__(256) void k_ln(const float* __restrict__ x,
                                            const float* __restrict__ gamma,
                                            short* __restrict__ xn) {
  int row = blockIdx.x;
  int t = threadIdx.x;
  const float4* xr = (const float4*)(x + (size_t)row * DIM);
  float4 v = xr[t];
  float s = v.x + v.y + v.z + v.w;
  float s2 = v.x * v.x + v.y * v.y + v.z * v.z + v.w * v.w;
#pragma unroll
  for (int m = 1; m < 64; m <<= 1) { s += __shfl_xor(s, m); s2 += __shfl_xor(s2, m); }
  __shared__ float red[8];
  int w = t >> 6;
  if ((t & 63) == 0) { red[w] = s; red[4 + w] = s2; }
  __syncthreads();
  s = red[0] + red[1] + red[2] + red[3];
  s2 = red[4] + red[5] + red[6] + red[7];
  float mu = s * (1.f / DIM);
  float rs = rsqrtf(s2 * (1.f / DIM) - mu * mu + 1e-5f);
  const float4* g4 = (const float4*)gamma;
  float4 g = g4[t];
  short4v o;
  o.x = f2bf((v.x - mu) * rs * g.x);
  o.y = f2bf((v.y - mu) * rs * g.y);
  o.z = f2bf((v.z - mu) * rs * g.z);
  o.w = f2bf((v.w - mu) * rs * g.w);
  ((short4v*)(xn + (size_t)row * DIM))[t] = o;
}

// ---------------- p1: fused qkv + silu(gate)*ffx GEMM, 4-phase schedule -----
// grid (37,16), 512 thr = 8 waves. 256-row A tiles, BK=64, 128KB LDS dbuf.
// fused blocks (bx<32): B = [F panel 128 rows; G panel 128 rows]. Quadrant
// phases (a,b): ph0=(0,F) ph1=(0,G) ph2=(1,G) ph3=(1,F); stage order of next
// tile: A0,B0,B1,A1 one pair/phase -> steady-state waits vmcnt(4), never 0.
// qkv blocks (bx>=32): simple stage-all + vmcnt(0) loop (13% of blocks).
__global__ __launch_bounds__(512, 2) void p1(const short* __restrict__ A,
                                             const short* __restrict__ Bt,
                                             short* __restrict__ qb,
                                             short* __restrict__ kbf,
                                             short* __restrict__ vtb,
                                             short* __restrict__ H) {
  extern __shared__ __align__(16) short S[];
  int tid = threadIdx.x, l = tid & 63, w = tid >> 6;
  int hw = blockIdx.y * 37 + blockIdx.x;      // 592 blocks
  int tile = (hw & 7) * 74 + (hw >> 3);       // XCD-contiguous remap
  int bx = tile % 37, by = tile / 37;
  int mBase = by * 256;
  bool fused = bx < 32;
  int b0row = fused ? (640 + bx * 128) : ((bx - 32) * 128);
  int b1row = 4736 + bx * 128;

  int srow = w * 8 + (l >> 3);
  int cs = (l & 7) ^ (l >> 3);
  const short* Ag = A + (size_t)(mBase + srow) * DIM + cs * 8;
  const short* Bg0 = Bt + (size_t)(b0row + srow) * DIM + cs * 8;
  const short* Bg1 = Bt + (size_t)(b1row + srow) * DIM + cs * 8;
  int dsto = w * 512 + l * 8;

#define STG_A0(kt, db) { _Pragma("unroll") for (int i = 0; i < 2; ++i) \
    g2l16(Ag + (size_t)(i * 64) * DIM + (kt) * 64, S + (db) * 16384 + i * 4096 + dsto); }
#define STG_A1(kt, db) { _Pragma("unroll") for (int i = 2; i < 4; ++i) \
    g2l16(Ag + (size_t)(i * 64) * DIM + (kt) * 64, S + (db) * 16384 + i * 4096 + dsto); }
#define STG_B0(kt, db) { _Pragma("unroll") for (int i = 0; i < 2; ++i) \
    g2l16(Bg0 + (size_t)(i * 64) * DIM + (kt) * 64, S + 32768 + (db) * 16384 + i * 4096 + dsto); }
#define STG_B1(kt, db) { _Pragma("unroll") for (int i = 0; i < 2; ++i) \
    g2l16(Bg1 + (size_t)(i * 64) * DIM + (kt) * 64, S + 32768 + (db) * 16384 + 8192 + i * 4096 + dsto); }

  const int NT = DIM / 64;  // 16
  int c0 = l & 15, kg = l >> 4, cx = l & 7;
  int ch0 = (kg ^ cx) * 8, ch1 = ((4 + kg) ^ cx) * 8;
  int r0 = (l >> 4) * 4;
  f32x4 zero = {0.f, 0.f, 0.f, 0.f};

  if (!fused) {
    // ---- qkv path: simple stage-all loop (R8 structure) ----
    STG_A0(0, 0); STG_A1(0, 0); STG_B0(0, 0);
    int wm = w >> 2, wn = w & 3;
    f32x4 acc[8][2];
#pragma unroll
    for (int m = 0; m < 8; ++m) { acc[m][0] = zero; acc[m][1] = zero; }
    for (int kt = 0; kt < NT; ++kt) {
      int db = kt & 1, dbn = db ^ 1;
      PH_W0;
      if (kt + 1 < NT) { STG_A0(kt + 1, dbn); STG_A1(kt + 1, dbn); STG_B0(kt + 1, dbn); }
      const short* Ab = S + db * 16384;
      const short* Bb = S + 32768 + db * 16384;
#pragma unroll
      for (int kkh = 0; kkh < 2; ++kkh) {
        int ch8 = kkh ? ch1 : ch0;
        short8 b0 = *(const short8*)(Bb + (wn * 32 + c0) * 64 + ch8);
        short8 b1 = *(const short8*)(Bb + (wn * 32 + 16 + c0) * 64 + ch8);
        __builtin_amdgcn_s_setprio(1);
#pragma unroll
        for (int m = 0; m < 8; ++m) {
          short8 a = *(const short8*)(Ab + (wm * 128 + m * 16 + c0) * 64 + ch8);
          acc[m][0] = __builtin_amdgcn_mfma_f32_16x16x32_bf16(a, b0, acc[m][0], 0, 0, 0);
          acc[m][1] = __builtin_amdgcn_mfma_f32_16x16x32_bf16(a, b1, acc[m][1], 0, 0, 0);
        }
        __builtin_amdgcn_s_setprio(0);
      }
    }
#pragma unroll
    for (int m = 0; m < 8; ++m)
#pragma unroll
      for (int n = 0; n < 2; ++n)
#pragma unroll
        for (int r = 0; r < 4; ++r) {
          float val = acc[m][n][r];
          int row = mBase + wm * 128 + m * 16 + r0 + r;
          int col = (bx - 32) * 128 + wn * 32 + n * 16 + c0;
          if (col < AINNER)
            qb[(size_t)row * AINNER + col] = f2bf(val);
          else if (col < AINNER + DH)
            kbf[(size_t)row * DH + (col - AINNER)] = f2bf(val);
          else
            vtb[((size_t)(row >> 11) * DH + (col - AINNER - DH)) * SEQ +
                (row & (SEQ - 1))] = f2bf(val);
        }
    return;
  }

  // ---- fused path: 4-phase quadrant schedule ----
  STG_A0(0, 0); STG_B0(0, 0); STG_B1(0, 0); STG_A1(0, 0);
  int ra = (w >> 2) * 64, rb = (w & 3) * 32;
  f32x4 acc[2][2][4][2];
#pragma unroll
  for (int a = 0; a < 2; ++a)
#pragma unroll
    for (int b = 0; b < 2; ++b)
#pragma unroll
      for (int m = 0; m < 4; ++m)
#pragma unroll
        for (int n = 0; n < 2; ++n) acc[a][b][m][n] = zero;

  for (int kt = 0; kt < NT; ++kt) {
    int db = kt & 1, dbn = db ^ 1;
    bool st = kt + 1 < NT;
    const short* Ab = S + db * 16384;
    const short* Bb = S + 32768 + db * 16384;
    short8 aF[4][2], bF[2][2], bG[2][2];
    // ---- ph0: quadrant (A0, F) ----
    PH_W4;
#pragma unroll
    for (int m = 0; m < 4; ++m) {
      aF[m][0] = *(const short8*)(Ab + (ra + m * 16 + c0) * 64 + ch0);
      aF[m][1] = *(const short8*)(Ab + (ra + m * 16 + c0) * 64 + ch1);
    }
#pragma unroll
    for (int n = 0; n < 2; ++n) {
      bF[n][0] = *(const short8*)(Bb + (rb + n * 16 + c0) * 64 + ch0);
      bF[n][1] = *(const short8*)(Bb + (rb + n * 16 + c0) * 64 + ch1);
    }
    if (st) STG_A0(kt + 1, dbn);
    __builtin_amdgcn_s_setprio(1);
#pragma unroll
    for (int m = 0; m < 4; ++m)
#pragma unroll
      for (int n = 0; n < 2; ++n) {
        acc[0][0][m][n] = __builtin_amdgcn_mfma_f32_16x16x32_bf16(aF[m][0], bF[n][0], acc[0][0][m][n], 0, 0, 0);
        acc[0][0][m][n] = __builtin_amdgcn_mfma_f32_16x16x32_bf16(aF[m][1], bF[n][1], acc[0][0][m][n], 0, 0, 0);
      }
    __builtin_amdgcn_s_setprio(0);
    // ---- ph1: quadrant (A0, G) ----
    if (st) PH_W4; else PH_W2;
#pragma unroll
    for (int n = 0; n < 2; ++n) {
      bG[n][0] = *(const short8*)(Bb + 8192 + (rb + n * 16 + c0) * 64 + ch0);
      bG[n][1] = *(const short8*)(Bb + 8192 + (rb + n * 16 + c0) * 64 + ch1);
    }
    if (st) STG_B0(kt + 1, dbn);
    __builtin_amdgcn_s_setprio(1);
#pragma unroll
    for (int m = 0; m < 4; ++m)
#pragma unroll
      for (int n = 0; n < 2; ++n) {
        acc[0][1][m][n] = __builtin_amdgcn_mfma_f32_16x16x32_bf16(aF[m][0], bG[n][0], acc[0][1][m][n], 0, 0, 0);
        acc[0][1][m][n] = __builtin_amdgcn_mfma_f32_16x16x32_bf16(aF[m][1], bG[n][1], acc[0][1][m][n], 0, 0, 0);
      }
    __builtin_amdgcn_s_setprio(0);
    // ---- ph2: quadrant (A1, G) ----
    if (st) PH_W4; else PH_W0;
#pragma unroll
    for (int m = 0; m < 4; ++m) {
      aF[m][0] = *(const short8*)(Ab + 8192 + (ra + m * 16 + c0) * 64 + ch0);
      aF[m][1] = *(const short8*)(Ab + 8192 + (ra + m * 16 + c0) * 64 + ch1);
    }
    if (st) STG_B1(kt + 1, dbn);
    __builtin_amdgcn_s_setprio(1);
#pragma unroll
    for (int m = 0; m < 4; ++m)
#pragma unroll
      for (int n = 0; n < 2; ++n) {
        acc[1][1][m][n] = __builtin_amdgcn_mfma_f32_16x16x32_bf16(aF[m][0], bG[n][0], acc[1][1][m][n], 0, 0, 0);
        acc[1][1][m][n] = __builtin_amdgcn_mfma_f32_16x16x32_bf16(aF[m][1], bG[n][1], acc[1][1][m][n], 0, 0, 0);
      }
    __builtin_amdgcn_s_setprio(0);
    // ---- ph3: quadrant (A1, F) ----
    PH_B;
    if (st) STG_A1(kt + 1, dbn);
    __builtin_amdgcn_s_setprio(1);
#pragma unroll
    for (int m = 0; m < 4; ++m)
#pragma unroll
      for (int n = 0; n < 2; ++n) {
        acc[1][0][m][n] = __builtin_amdgcn_mfma_f32_16x16x32_bf16(aF[m][0], bF[n][0], acc[1][0][m][n], 0, 0, 0);
        acc[1][0][m][n] = __builtin_amdgcn_mfma_f32_16x16x32_bf16(aF[m][1], bF[n][1], acc[1][0][m][n], 0, 0, 0);
      }
    __builtin_amdgcn_s_setprio(0);
  }
#undef STG_A0
#undef STG_A1
#undef STG_B0
#undef STG_B1

#pragma unroll
  for (int a = 0; a < 2; ++a)
#pragma unroll
    for (int m = 0; m < 4; ++m)
#pragma unroll
      for (int n = 0; n < 2; ++n)
#pragma unroll
        for (int r = 0; r < 4; ++r) {
          int row = mBase + a * 128 + ra + m * 16 + r0 + r;
          int col = bx * 128 + rb + n * 16 + c0;   // F-panel col 0..4095
          float g = acc[a][1][m][n][r];
          float sg = g / (1.f + __expf(-g));
          H[(size_t)row * HCOLS + AINNER + col] = f2bf(sg * acc[a][0][m][n][r]);
        }
}

// ---------------- out-GEMM: 256x256 split-K=4, 4-phase schedule -------------
__global__ __launch_bounds__(512, 2) void gemm_s(const short* __restrict__ A,
                                                 const short* __restrict__ Bt,
                                                 short* __restrict__ part) {
  extern __shared__ __align__(16) short S[];
  int tid = threadIdx.x, l = tid & 63, w = tid >> 6;
  int hw = (blockIdx.z * 16 + blockIdx.y) * 4 + blockIdx.x;  // 256 blocks
  int tile = (hw & 7) * 32 + (hw >> 3);
  int bx = tile & 3, by = (tile >> 2) & 15, bz = tile >> 6;
  int mBase = by * 256, nBase = bx * 256;
  int kOff = bz * 1152;

  int srow = w * 8 + (l >> 3);
  int cs = (l & 7) ^ (l >> 3);
  const short* Ag = A + (size_t)(mBase + srow) * HCOLS + kOff + cs * 8;
  const short* Bg = Bt + (size_t)(nBase + srow) * HCOLS + kOff + cs * 8;
  int dsto = w * 512 + l * 8;

#define SG_A0(kt, db) { _Pragma("unroll") for (int i = 0; i < 2; ++i) \
    g2l16(Ag + (size_t)(i * 64) * HCOLS + (kt) * 64, S + (db) * 16384 + i * 4096 + dsto); }
#define SG_A1(kt, db) { _Pragma("unroll") for (int i = 2; i < 4; ++i) \
    g2l16(Ag + (size_t)(i * 64) * HCOLS + (kt) * 64, S + (db) * 16384 + i * 4096 + dsto); }
#define SG_B0(kt, db) { _Pragma("unroll") for (int i = 0; i < 2; ++i) \
    g2l16(Bg + (size_t)(i * 64) * HCOLS + (kt) * 64, S + 32768 + (db) * 16384 + i * 4096 + dsto); }
#define SG_B1(kt, db) { _Pragma("unroll") for (int i = 2; i < 4; ++i) \
    g2l16(Bg + (size_t)(i * 64) * HCOLS + (kt) * 64, S + 32768 + (db) * 16384 + i * 4096 + dsto); }

  const int NT = 18;
  SG_A0(0, 0); SG_B0(0, 0); SG_B1(0, 0); SG_A1(0, 0);

  int c0 = l & 15, kg = l >> 4, cx = l & 7;
  int ch0 = (kg ^ cx) * 8, ch1 = ((4 + kg) ^ cx) * 8;
  int ra = (w >> 2) * 64, rb = (w & 3) * 32;
  f32x4 zero = {0.f, 0.f, 0.f, 0.f};
  f32x4 acc[2][2][4][2];
#pragma unroll
  for (int a = 0; a < 2; ++a)
#pragma unroll
    for (int b = 0; b < 2; ++b)
#pragma unroll
      for (int m = 0; m < 4; ++m)
#pragma unroll
        for (int n = 0; n < 2; ++n) acc[a][b][m][n] = zero;

  for (int kt = 0; kt < NT; ++kt) {
    int db = kt & 1, dbn = db ^ 1;
    bool st = kt + 1 < NT;
    const short* Ab = S + db * 16384;
    const short* Bb = S + 32768 + db * 16384;
    short8 aF[4][2], bF[2][2], bG[2][2];
    PH_W4;
#pragma unroll
    for (int m = 0; m < 4; ++m) {
      aF[m][0] = *(const short8*)(Ab + (ra + m * 16 + c0) * 64 + ch0);
      aF[m][1] = *(const short8*)(Ab + (ra + m * 16 + c0) * 64 + ch1);
    }
#pragma unroll
    for (int n = 0; n < 2; ++n) {
      bF[n][0] = *(const short8*)(Bb + (rb + n * 16 + c0) * 64 + ch0);
      bF[n][1] = *(const short8*)(Bb + (rb + n * 16 + c0) * 64 + ch1);
    }
    if (st) SG_A0(kt + 1, dbn);
    __builtin_amdgcn_s_setprio(1);
#pragma unroll
    for (int m = 0; m < 4; ++m)
#pragma unroll
      for (int n = 0; n < 2; ++n) {
        acc[0][0][m][n] = __builtin_amdgcn_mfma_f32_16x16x32_bf16(aF[m][0], bF[n][0], acc[0][0][m][n], 0, 0, 0);
        acc[0][0][m][n] = __builtin_amdgcn_mfma_f32_16x16x32_bf16(aF[m][1], bF[n][1], acc[0][0][m][n], 0, 0, 0);
      }
    __builtin_amdgcn_s_setprio(0);
    if (st) PH_W4; else PH_W2;
#pragma unroll
    for (int n = 0; n < 2; ++n) {
      bG[n][0] = *(const short8*)(Bb + 8192 + (rb + n * 16 + c0) * 64 + ch0);
      bG[n][1] = *(const short8*)(Bb + 8192 + (rb + n * 16 + c0) * 64 + ch1);
    }
    if (st) SG_B0(kt + 1, dbn);
    __builtin_amdgcn_s_setprio(1);
#pragma unroll
    for (int m = 0; m < 4; ++m)
#pragma unroll
      for (int n = 0; n < 2; ++n) {
        acc[0][1][m][n] = __builtin_amdgcn_mfma_f32_16x16x32_bf16(aF[m][0], bG[n][0], acc[0][1][m][n], 0, 0, 0);
        acc[0][1][m][n] = __builtin_amdgcn_mfma_f32_16x16x32_bf16(aF[m][1], bG[n][1], acc[0][1][m][n], 0, 0, 0);
      }
    __builtin_amdgcn_s_setprio(0);
    if (st) PH_W4; else PH_W0;
#pragma unroll
    for (int m = 0; m < 4; ++m) {
      aF[m][0] = *(const short8*)(Ab + 8192 + (ra + m * 16 + c0) * 64 + ch0);
      aF[m][1] = *(const short8*)(Ab + 8192 + (ra + m * 16 + c0) * 64 + ch1);
    }
    if (st) SG_B1(kt + 1, dbn);
    __builtin_amdgcn_s_setprio(1);
#pragma unroll
    for (int m = 0; m < 4; ++m)
#pragma unroll
      for (int n = 0; n < 2; ++n) {
        acc[1][1][m][n] = __builtin_amdgcn_mfma_f32_16x16x32_bf16(aF[m][0], bG[n][0], acc[1][1][m][n], 0, 0, 0);
        acc[1][1][m][n] = __builtin_amdgcn_mfma_f32_16x16x32_bf16(aF[m][1], bG[n][1], acc[1][1][m][n], 0, 0, 0);
      }
    __builtin_amdgcn_s_setprio(0);
    PH_B;
    if (st) SG_A1(kt + 1, dbn);
    __builtin_amdgcn_s_setprio(1);
#pragma unroll
    for (int m = 0; m < 4; ++m)
#pragma unroll
      for (int n = 0; n < 2; ++n) {
        acc[1][0][m][n] = __builtin_amdgcn_mfma_f32_16x16x32_bf16(aF[m][0], bF[n][0], acc[1][0][m][n], 0, 0, 0);
        acc[1][0][m][n] = __builtin_amdgcn_mfma_f32_16x16x32_bf16(aF[m][1], bF[n][1], acc[1][0][m][n], 0, 0, 0);
      }
    __builtin_amdgcn_s_setprio(0);
  }
#undef SG_A0
#undef SG_A1
#undef SG_B0
#undef SG_B1

  int r0 = (l >> 4) * 4;
#pragma unroll
  for (int a = 0; a < 2; ++a)
#pragma unroll
    for (int b = 0; b < 2; ++b)
#pragma unroll
      for (int m = 0; m < 4; ++m)
#pragma unroll
        for (int n = 0; n < 2; ++n)
#pragma unroll
          for (int r = 0; r < 4; ++r) {
            int row = mBase + a * 128 + ra + m * 16 + r0 + r;
            int col = nBase + b * 128 + rb + n * 16 + c0;
            part[(size_t)bz * (NTOK * DIM) + (size_t)row * DIM + col] = f2bf(acc[a][b][m][n][r]);
          }
}

__global__ __launch_bounds__(256) void k_red(const short* __restrict__ part,
                                             float* __restrict__ out) {
  int i = (blockIdx.x * 256 + threadIdx.x) * 4;
  float4 s = {0.f, 0.f, 0.f, 0.f};
#pragma unroll
  for (int ks = 0; ks < 4; ++ks) {
    short4v v = *(const short4v*)(part + (size_t)ks * (NTOK * DIM) + i);
    s.x += bf2f(v.x); s.y += bf2f(v.y); s.z += bf2f(v.z); s.w += bf2f(v.w);
  }
  *(float4*)(out + i) = s;
}

// ---------------- flash attention (unchanged) -------------------------------
__global__ __launch_bounds__(256) void k_attn(const short* __restrict__ qb,
                                              const short* __restrict__ kb,
                                              const short* __restrict__ vt,
                                              short* __restrict__ H) {
  __shared__ __align__(16) short Qs[64 * 64];
  __shared__ __align__(16) short Ks[128 * 64];
  __shared__ __align__(16) short Vs[64 * 128];
  __shared__ __align__(16) short Ps[4][16 * 128];
  int t = threadIdx.x, l = t & 63, w = t >> 6;
  int qt = blockIdx.x, bh = blockIdx.y;
  int b = bh >> 3, h = bh & 7;
  int q0 = qt * 64;

  int srow = w * 8 + (l >> 3);
  int schunk = (l & 7) ^ (l >> 3);
  {
    const short* Qg = qb + (size_t)(b * SEQ + q0 + srow) * AINNER + h * DH + schunk * 8;
    short* qs = Qs + w * 512 + l * 8;
#pragma unroll
    for (int i = 0; i < 2; ++i) g2l16(Qg + (size_t)(i * 32) * AINNER, qs + i * 2048);
  }
  const short* Kg = kb + (size_t)(b * SEQ + srow) * DH + schunk * 8;
  short* ksl = Ks + w * 512 + l * 8;
  int vrow = w * 4 + (l >> 4);
  int vchunk = (l & 15) ^ (vrow & 7);
  const short* Vg = vt + (size_t)b * DH * SEQ + (size_t)vrow * SEQ + vchunk * 8;
  short* vsl = Vs + w * 512 + l * 8;

#pragma unroll
  for (int i = 0; i < 4; ++i) {
    g2l16(Kg + (size_t)(i * 32) * DH, ksl + i * 2048);
    g2l16(Vg + (size_t)(i * 16) * SEQ, vsl + i * 2048);
  }

  float m_run[4], l_run[4];
  f32x4 zero = {0.f, 0.f, 0.f, 0.f};
  f32x4 Oacc[4];
#pragma unroll
  for (int r = 0; r < 4; ++r) { m_run[r] = -1e30f; l_run[r] = 0.f; }
#pragma unroll
  for (int n = 0; n < 4; ++n) Oacc[n] = zero;

  int c0 = l & 15, kg = l >> 4, cx = l & 7;
  short* pw = Ps[w];

  for (int kv0 = 0; kv0 < SEQ; kv0 += 128) {
    asm volatile("s_waitcnt vmcnt(0)\ns_barrier" ::: "memory");

    f32x4 sacc[8];
#pragma unroll
    for (int n = 0; n < 8; ++n) sacc[n] = zero;
#pragma unroll
    for (int kk = 0; kk < 2; ++kk) {
      int rr = w * 16 + c0;
      short8 aq = *(const short8*)(Qs + rr * 64 + ((kk * 4 + kg) ^ cx) * 8);
#pragma unroll
      for (int n = 0; n < 8; ++n) {
        int kr = n * 16 + c0;
        short8 bk = *(const short8*)(Ks + kr * 64 + ((kk * 4 + kg) ^ cx) * 8);
        sacc[n] = __builtin_amdgcn_mfma_f32_16x16x32_bf16(aq, bk, sacc[n], 0, 0, 0);
      }
    }
#pragma unroll
    for (int r = 0; r < 4; ++r) {
      float mx = -1e30f;
#pragma unroll
      for (int n = 0; n < 8; ++n) {
        sacc[n][r] *= 0.125f;
        mx = fmaxf(mx, sacc[n][r]);
      }
#pragma unroll
      for (int msk = 1; msk < 16; msk <<= 1) mx = fmaxf(mx, __shfl_xor(mx, msk));
      float nm = fmaxf(m_run[r], mx);
      float corr = __expf(m_run[r] - nm);
      m_run[r] = nm;
      float rs = 0.f;
#pragma unroll
      for (int n = 0; n < 8; ++n) {
        float p = __expf(sacc[n][r] - nm);
        sacc[n][r] = p;
        rs += p;
      }
#pragma unroll
      for (int msk = 1; msk < 16; msk <<= 1) rs += __shfl_xor(rs, msk);
      l_run[r] = l_run[r] * corr + rs;
      Oacc[0][r] *= corr; Oacc[1][r] *= corr; Oacc[2][r] *= corr; Oacc[3][r] *= corr;
    }
#pragma unroll
    for (int n = 0; n < 8; ++n)
#pragma unroll
      for (int r = 0; r < 4; ++r) {
        int pr = (l >> 4) * 4 + r;
        int pc = n * 16 + c0;
        pw[pr * 128 + ((pc >> 3) ^ (pr & 7)) * 8 + (pc & 7)] = f2bf(sacc[n][r]);
      }
    asm volatile("s_waitcnt lgkmcnt(0)" ::: "memory");
#pragma unroll
    for (int kk = 0; kk < 4; ++kk) {
      int pr = c0;
      short8 ap = *(const short8*)(pw + pr * 128 + ((kk * 4 + kg) ^ cx) * 8);
#pragma unroll
      for (int n = 0; n < 4; ++n) {
        int vr = n * 16 + c0;
        short8 bv = *(const short8*)(Vs + vr * 128 + ((kk * 4 + kg) ^ (vr & 7)) * 8);
        Oacc[n] = __builtin_amdgcn_mfma_f32_16x16x32_bf16(ap, bv, Oacc[n], 0, 0, 0);
      }
    }
    __syncthreads();
    int nx = kv0 + 128;
    if (nx < SEQ) {
#pragma unroll
      for (int i = 0; i < 4; ++i) {
        g2l16(Kg + (size_t)(nx + i * 32) * DH, ksl + i * 2048);
        g2l16(Vg + nx + (size_t)(i * 16) * SEQ, vsl + i * 2048);
      }
    }
  }
#pragma unroll
  for (int r = 0; r < 4; ++r) {
    float inv = 1.f / l_run[r];
    int row = b * SEQ + q0 + w * 16 + (l >> 4) * 4 + r;
#pragma unroll
    for (int n = 0; n < 4; ++n) {
      int col = h * DH + n * 16 + c0;
      H[(size_t)row * HCOLS + col] = f2bf(Oacc[n][r] * inv);
    }
  }
}

// ----------------------------------------------------------------------------
extern "C" void kernel_launch(void* const* d_in, const int* in_sizes, int n_in,
                              void* d_out, int out_size, void* d_ws, size_t ws_size,
                              hipStream_t stream) {
  const float* x     = (const float*)d_in[0];
  const float* gamma = (const float*)d_in[1];
  const float* w_f   = (const float*)d_in[2];
  const float* w_ao  = (const float*)d_in[3];
  const float* w_fo  = (const float*)d_in[4];
  float* out = (float*)d_out;

  char* ws = (char*)d_ws;
  size_t o = 0;
  short* WtF = (short*)(ws + o); o += (size_t)FUSED * DIM * 2;
  short* Wt2 = (short*)(ws + o); o += (size_t)DIM * HCOLS * 2;
  short* xn  = (short*)(ws + o); o += (size_t)NTOK * DIM * 2;
  short* qb  = (short*)(ws + o); o += (size_t)NTOK * AINNER * 2;
  short* kbf = (short*)(ws + o); o += (size_t)NTOK * DH * 2;
  short* vtb = (short*)(ws + o); o += (size_t)NTOK * DH * 2;
  short* H   = (short*)(ws + o); o += (size_t)NTOK * HCOLS * 2;
  short* part = (short*)(ws + o);

  k_transpose_wf<<<dim3(FUSED / 32, DIM / 32), 256, 0, stream>>>(w_f, WtF);
  k_transpose_w2<<<dim3(DIM / 32, HCOLS / 32), 256, 0, stream>>>(w_ao, w_fo, Wt2);
  k_ln<<<NTOK, 256, 0, stream>>>(x, gamma, xn);
  p1<<<dim3(37, 16), 512, 131072, stream>>>(xn, WtF, qb, kbf, vtb, H);
  k_attn<<<dim3(32, 16), 256, 0, stream>>>(qb, kbf, vtb, H);
  gemm_s<<<dim3(4, 16, 4), 512, 131072, stream>>>(H, Wt2, part);
  k_red<<<NTOK * DIM / 1024, 256, 0, stream>>>(part, out);
}

// Round 10
// 211.132 us; speedup vs baseline: 1.2919x; 1.0026x over previous
//
#include <hip/hip_runtime.h>
#include <hip/hip_bf16.h>
#include <stdint.h>

#define DIM     1024
#define SEQ     2048
#define NTOK    4096
#define HEADS   8
#define DH      64
#define AINNER  512
#define FFI     4096
#define FUSED   8832
#define HCOLS   4608   // 512 attn-out cols + 4096 gated-ff cols

typedef __attribute__((ext_vector_type(8))) short short8;
typedef __attribute__((ext_vector_type(4))) short short4v;
typedef __attribute__((ext_vector_type(4))) float f32x4;

__device__ __forceinline__ short f2bf(float f) {
  union { float f; uint32_t u; } v; v.f = f;
  uint32_t r = v.u + 0x7fffu + ((v.u >> 16) & 1u);
  return (short)(r >> 16);
}
__device__ __forceinline__ float bf2f(short s) {
  union { uint32_t u; float f; } v; v.u = ((uint32_t)(uint16_t)s) << 16;
  return v.f;
}
__device__ __forceinline__ void g2l16(const void* g, void* l) {
  __builtin_amdgcn_global_load_lds((const __attribute__((address_space(1))) void*)g,
                                   (__attribute__((address_space(3))) void*)l, 16, 0, 0);
}

#define PH_W4 asm volatile("s_waitcnt vmcnt(4)\ns_barrier" ::: "memory")
#define PH_W2 asm volatile("s_waitcnt vmcnt(2)\ns_barrier" ::: "memory")
#define PH_W0 asm volatile("s_waitcnt vmcnt(0)\ns_barrier" ::: "memory")
#define PH_B  asm volatile("s_barrier" ::: "memory")

// ---------------- transpose + f32->bf16 convert -----------------------------
__global__ __launch_bounds__(256) void k_transpose_wf(const float* __restrict__ src,
                                                      short* __restrict__ dst) {
  __shared__ short tile[32][33];
  int c0 = blockIdx.x * 32;
  int r0 = blockIdx.y * 32;
  int tx = threadIdx.x & 31, ty = threadIdx.x >> 5;
#pragma unroll
  for (int i = 0; i < 32; i += 8)
    tile[ty + i][tx] = f2bf(src[(size_t)(r0 + ty + i) * FUSED + c0 + tx]);
  __syncthreads();
#pragma unroll
  for (int i = 0; i < 32; i += 8)
    dst[(size_t)(c0 + ty + i) * DIM + r0 + tx] = tile[tx][ty + i];
}

__global__ __launch_bounds__(256) void k_transpose_w2(const float* __restrict__ wao,
                                                      const float* __restrict__ wfo,
                                                      short* __restrict__ dst) {
  __shared__ short tile[32][33];
  int c0 = blockIdx.x * 32;
  int r0 = blockIdx.y * 32;
  int tx = threadIdx.x & 31, ty = threadIdx.x >> 5;
#pragma unroll
  for (int i = 0; i < 32; i += 8) {
    int r = r0 + ty + i;
    float v = (r < AINNER) ? wao[(size_t)r * DIM + c0 + tx]
                           : wfo[(size_t)(r - AINNER) * DIM + c0 + tx];
    tile[ty + i][tx] = f2bf(v);
  }
  __syncthreads();
#pragma unroll
  for (int i = 0; i < 32; i += 8)
    dst[(size_t)(c0 + ty + i) * HCOLS + r0 + tx] = tile[tx][ty + i];
}

// ---------------- layernorm -------------------------------------------------
__global__ __launch_bounds__(256) void k_ln(const float* __restrict__ x,
                                            const float* __restrict__ gamma,
                                            short* __restrict__ xn) {
  int row = blockIdx.x;
  int t = threadIdx.x;
  const float4* xr = (const float4*)(x + (size_t)row * DIM);
  float4 v = xr[t];
  float s = v.x + v.y + v.z + v.w;
  float s2 = v.x * v.x + v.y * v.y + v.z * v.z + v.w * v.w;
#pragma unroll
  for (int m = 1; m < 64; m <<= 1) { s += __shfl_xor(s, m); s2 += __shfl_xor(s2, m); }
  __shared__ float red[8];
  int w = t >> 6;
  if ((t & 63) == 0) { red[w] = s; red[4 + w] = s2; }
  __syncthreads();
  s = red[0] + red[1] + red[2] + red[3];
  s2 = red[4] + red[5] + red[6] + red[7];
  float mu = s * (1.f / DIM);
  float rs = rsqrtf(s2 * (1.f / DIM) - mu * mu + 1e-5f);
  const float4* g4 = (const float4*)gamma;
  float4 g = g4[t];
  short4v o;
  o.x = f2bf((v.x - mu) * rs * g.x);
  o.y = f2bf((v.y - mu) * rs * g.y);
  o.z = f2bf((v.z - mu) * rs * g.z);
  o.w = f2bf((v.w - mu) * rs * g.w);
  ((short4v*)(xn + (size_t)row * DIM))[t] = o;
}

// ---------------- p1: fused qkv + silu(gate)*ffx GEMM, convoy phases --------
// grid (37,16), 512 thr = 8 waves. 256-row A tiles, BK=64, 128KB LDS dbuf.
// fused blocks: quadrant phases ph0=(A0,F) ph1=(A0,G) ph2=(A1,G) ph3=(A1,F);
// per phase: {vmcnt(4); barrier; ds_reads; stage pair; barrier; MFMA} —
// two barriers convoy reads/MFMA across waves; ph3 register-only, no barriers.
// Tile map: fused tiles first, 80 qkv blocks dispatched LAST (tail balance);
// XCD chunk c owns by={2c,2c+1} (A-row L2 locality).
__global__ __launch_bounds__(512, 2) void p1(const short* __restrict__ A,
                                             const short* __restrict__ Bt,
                                             short* __restrict__ qb,
                                             short* __restrict__ kbf,
                                             short* __restrict__ vtb,
                                             short* __restrict__ H) {
  extern __shared__ __align__(16) short S[];
  int tid = threadIdx.x, l = tid & 63, w = tid >> 6;
  int hw = blockIdx.y * 37 + blockIdx.x;      // 592 blocks
  int tile = (hw & 7) * 74 + (hw >> 3);       // XCD-contiguous remap
  int c = tile / 74, j = tile % 74;           // chunk c: 64 fused + 10 qkv
  bool fused = j < 64;
  int bx, by;
  if (fused) { int f = c * 64 + j; by = f >> 5; bx = f & 31; }
  else       { int q = c * 10 + (j - 64); by = q / 5; bx = 32 + q % 5; }
  int mBase = by * 256;
  int b0row = fused ? (640 + bx * 128) : ((bx - 32) * 128);
  int b1row = 4736 + bx * 128;

  int srow = w * 8 + (l >> 3);
  int cs = (l & 7) ^ (l >> 3);
  const short* Ag = A + (size_t)(mBase + srow) * DIM + cs * 8;
  const short* Bg0 = Bt + (size_t)(b0row + srow) * DIM + cs * 8;
  const short* Bg1 = Bt + (size_t)(b1row + srow) * DIM + cs * 8;
  int dsto = w * 512 + l * 8;

#define STG_A0(kt, db) { _Pragma("unroll") for (int i = 0; i < 2; ++i) \
    g2l16(Ag + (size_t)(i * 64) * DIM + (kt) * 64, S + (db) * 16384 + i * 4096 + dsto); }
#define STG_A1(kt, db) { _Pragma("unroll") for (int i = 2; i < 4; ++i) \
    g2l16(Ag + (size_t)(i * 64) * DIM + (kt) * 64, S + (db) * 16384 + i * 4096 + dsto); }
#define STG_B0(kt, db) { _Pragma("unroll") for (int i = 0; i < 2; ++i) \
    g2l16(Bg0 + (size_t)(i * 64) * DIM + (kt) * 64, S + 32768 + (db) * 16384 + i * 4096 + dsto); }
#define STG_B1(kt, db) { _Pragma("unroll") for (int i = 0; i < 2; ++i) \
    g2l16(Bg1 + (size_t)(i * 64) * DIM + (kt) * 64, S + 32768 + (db) * 16384 + 8192 + i * 4096 + dsto); }

  const int NT = DIM / 64;  // 16
  int c0 = l & 15, kg = l >> 4, cx = l & 7;
  int ch0 = (kg ^ cx) * 8, ch1 = ((4 + kg) ^ cx) * 8;
  int r0 = (l >> 4) * 4;
  f32x4 zero = {0.f, 0.f, 0.f, 0.f};

  if (!fused) {
    // ---- qkv path: simple stage-all loop ----
    STG_A0(0, 0); STG_A1(0, 0); STG_B0(0, 0);
    int wm = w >> 2, wn = w & 3;
    f32x4 acc[8][2];
#pragma unroll
    for (int m = 0; m < 8; ++m) { acc[m][0] = zero; acc[m][1] = zero; }
    for (int kt = 0; kt < NT; ++kt) {
      int db = kt & 1, dbn = db ^ 1;
      PH_W0;
      if (kt + 1 < NT) { STG_A0(kt + 1, dbn); STG_A1(kt + 1, dbn); STG_B0(kt + 1, dbn); }
      const short* Ab = S + db * 16384;
      const short* Bb = S + 32768 + db * 16384;
#pragma unroll
      for (int kkh = 0; kkh < 2; ++kkh) {
        int ch8 = kkh ? ch1 : ch0;
        short8 b0 = *(const short8*)(Bb + (wn * 32 + c0) * 64 + ch8);
        short8 b1 = *(const short8*)(Bb + (wn * 32 + 16 + c0) * 64 + ch8);
        __builtin_amdgcn_s_setprio(1);
#pragma unroll
        for (int m = 0; m < 8; ++m) {
          short8 a = *(const short8*)(Ab + (wm * 128 + m * 16 + c0) * 64 + ch8);
          acc[m][0] = __builtin_amdgcn_mfma_f32_16x16x32_bf16(a, b0, acc[m][0], 0, 0, 0);
          acc[m][1] = __builtin_amdgcn_mfma_f32_16x16x32_bf16(a, b1, acc[m][1], 0, 0, 0);
        }
        __builtin_amdgcn_s_setprio(0);
      }
    }
#pragma unroll
    for (int m = 0; m < 8; ++m)
#pragma unroll
      for (int n = 0; n < 2; ++n)
#pragma unroll
        for (int r = 0; r < 4; ++r) {
          float val = acc[m][n][r];
          int row = mBase + wm * 128 + m * 16 + r0 + r;
          int col = (bx - 32) * 128 + wn * 32 + n * 16 + c0;
          if (col < AINNER)
            qb[(size_t)row * AINNER + col] = f2bf(val);
          else if (col < AINNER + DH)
            kbf[(size_t)row * DH + (col - AINNER)] = f2bf(val);
          else
            vtb[((size_t)(row >> 11) * DH + (col - AINNER - DH)) * SEQ +
                (row & (SEQ - 1))] = f2bf(val);
        }
    return;
  }

  // ---- fused path: 4-phase convoy schedule ----
  STG_A0(0, 0); STG_B0(0, 0); STG_B1(0, 0); STG_A1(0, 0);
  int ra = (w >> 2) * 64, rb = (w & 3) * 32;
  f32x4 acc[2][2][4][2];
#pragma unroll
  for (int a = 0; a < 2; ++a)
#pragma unroll
    for (int b = 0; b < 2; ++b)
#pragma unroll
      for (int m = 0; m < 4; ++m)
#pragma unroll
        for (int n = 0; n < 2; ++n) acc[a][b][m][n] = zero;

  for (int kt = 0; kt < NT; ++kt) {
    int db = kt & 1, dbn = db ^ 1;
    bool st = kt + 1 < NT;
    const short* Ab = S + db * 16384;
    const short* Bb = S + 32768 + db * 16384;
    short8 a1[4][2], a2[4][2], bF[2][2], bG[2][2];
    // ---- ph0: (A0, F) ----
    PH_W4;
#pragma unroll
    for (int m = 0; m < 4; ++m) {
      a1[m][0] = *(const short8*)(Ab + (ra + m * 16 + c0) * 64 + ch0);
      a1[m][1] = *(const short8*)(Ab + (ra + m * 16 + c0) * 64 + ch1);
    }
#pragma unroll
    for (int n = 0; n < 2; ++n) {
      bF[n][0] = *(const short8*)(Bb + (rb + n * 16 + c0) * 64 + ch0);
      bF[n][1] = *(const short8*)(Bb + (rb + n * 16 + c0) * 64 + ch1);
    }
    if (st) STG_A0(kt + 1, dbn);
    PH_B;
    __builtin_amdgcn_s_setprio(1);
#pragma unroll
    for (int m = 0; m < 4; ++m)
#pragma unroll
      for (int n = 0; n < 2; ++n) {
        acc[0][0][m][n] = __builtin_amdgcn_mfma_f32_16x16x32_bf16(a1[m][0], bF[n][0], acc[0][0][m][n], 0, 0, 0);
        acc[0][0][m][n] = __builtin_amdgcn_mfma_f32_16x16x32_bf16(a1[m][1], bF[n][1], acc[0][0][m][n], 0, 0, 0);
      }
    __builtin_amdgcn_s_setprio(0);
    // ---- ph1: (A0, G) ----
    if (st) PH_W4; else PH_W2;
#pragma unroll
    for (int n = 0; n < 2; ++n) {
      bG[n][0] = *(const short8*)(Bb + 8192 + (rb + n * 16 + c0) * 64 + ch0);
      bG[n][1] = *(const short8*)(Bb + 8192 + (rb + n * 16 + c0) * 64 + ch1);
    }
    if (st) STG_B0(kt + 1, dbn);
    PH_B;
    __builtin_amdgcn_s_setprio(1);
#pragma unroll
    for (int m = 0; m < 4; ++m)
#pragma unroll
      for (int n = 0; n < 2; ++n) {
        acc[0][1][m][n] = __builtin_amdgcn_mfma_f32_16x16x32_bf16(a1[m][0], bG[n][0], acc[0][1][m][n], 0, 0, 0);
        acc[0][1][m][n] = __builtin_amdgcn_mfma_f32_16x16x32_bf16(a1[m][1], bG[n][1], acc[0][1][m][n], 0, 0, 0);
      }
    __builtin_amdgcn_s_setprio(0);
    // ---- ph2: (A1, G) ----
    if (st) PH_W4; else PH_W0;
#pragma unroll
    for (int m = 0; m < 4; ++m) {
      a2[m][0] = *(const short8*)(Ab + 8192 + (ra + m * 16 + c0) * 64 + ch0);
      a2[m][1] = *(const short8*)(Ab + 8192 + (ra + m * 16 + c0) * 64 + ch1);
    }
    if (st) STG_B1(kt + 1, dbn);
    PH_B;
    __builtin_amdgcn_s_setprio(1);
#pragma unroll
    for (int m = 0; m < 4; ++m)
#pragma unroll
      for (int n = 0; n < 2; ++n) {
        acc[1][1][m][n] = __builtin_amdgcn_mfma_f32_16x16x32_bf16(a2[m][0], bG[n][0], acc[1][1][m][n], 0, 0, 0);
        acc[1][1][m][n] = __builtin_amdgcn_mfma_f32_16x16x32_bf16(a2[m][1], bG[n][1], acc[1][1][m][n], 0, 0, 0);
      }
    __builtin_amdgcn_s_setprio(0);
    // ---- ph3: (A1, F) — register-only, no barriers ----
    if (st) STG_A1(kt + 1, dbn);
    __builtin_amdgcn_s_setprio(1);
#pragma unroll
    for (int m = 0; m < 4; ++m)
#pragma unroll
      for (int n = 0; n < 2; ++n) {
        acc[1][0][m][n] = __builtin_amdgcn_mfma_f32_16x16x32_bf16(a2[m][0], bF[n][0], acc[1][0][m][n], 0, 0, 0);
        acc[1][0][m][n] = __builtin_amdgcn_mfma_f32_16x16x32_bf16(a2[m][1], bF[n][1], acc[1][0][m][n], 0, 0, 0);
      }
    __builtin_amdgcn_s_setprio(0);
  }
#undef STG_A0
#undef STG_A1
#undef STG_B0
#undef STG_B1

#pragma unroll
  for (int a = 0; a < 2; ++a)
#pragma unroll
    for (int m = 0; m < 4; ++m)
#pragma unroll
      for (int n = 0; n < 2; ++n)
#pragma unroll
        for (int r = 0; r < 4; ++r) {
          int row = mBase + a * 128 + ra + m * 16 + r0 + r;
          int col = bx * 128 + rb + n * 16 + c0;   // F-panel col 0..4095
          float g = acc[a][1][m][n][r];
          float sg = g / (1.f + __expf(-g));
          H[(size_t)row * HCOLS + AINNER + col] = f2bf(sg * acc[a][0][m][n][r]);
        }
}

// ---------------- out-GEMM: 256x256 split-K=4, convoy phases ----------------
__global__ __launch_bounds__(512, 2) void gemm_s(const short* __restrict__ A,
                                                 const short* __restrict__ Bt,
                                                 short* __restrict__ part) {
  extern __shared__ __align__(16) short S[];
  int tid = threadIdx.x, l = tid & 63, w = tid >> 6;
  int hw = (blockIdx.z * 16 + blockIdx.y) * 4 + blockIdx.x;  // 256 blocks
  int tile = (hw & 7) * 32 + (hw >> 3);
  int bx = tile & 3, by = (tile >> 2) & 15, bz = tile >> 6;
  int mBase = by * 256, nBase = bx * 256;
  int kOff = bz * 1152;

  int srow = w * 8 + (l >> 3);
  int cs = (l & 7) ^ (l >> 3);
  const short* Ag = A + (size_t)(mBase + srow) * HCOLS + kOff + cs * 8;
  const short* Bg = Bt + (size_t)(nBase + srow) * HCOLS + kOff + cs * 8;
  int dsto = w * 512 + l * 8;

#define SG_A0(kt, db) { _Pragma("unroll") for (int i = 0; i < 2; ++i) \
    g2l16(Ag + (size_t)(i * 64) * HCOLS + (kt) * 64, S + (db) * 16384 + i * 4096 + dsto); }
#define SG_A1(kt, db) { _Pragma("unroll") for (int i = 2; i < 4; ++i) \
    g2l16(Ag + (size_t)(i * 64) * HCOLS + (kt) * 64, S + (db) * 16384 + i * 4096 + dsto); }
#define SG_B0(kt, db) { _Pragma("unroll") for (int i = 0; i < 2; ++i) \
    g2l16(Bg + (size_t)(i * 64) * HCOLS + (kt) * 64, S + 32768 + (db) * 16384 + i * 4096 + dsto); }
#define SG_B1(kt, db) { _Pragma("unroll") for (int i = 2; i < 4; ++i) \
    g2l16(Bg + (size_t)(i * 64) * HCOLS + (kt) * 64, S + 32768 + (db) * 16384 + i * 4096 + dsto); }

  const int NT = 18;
  SG_A0(0, 0); SG_B0(0, 0); SG_B1(0, 0); SG_A1(0, 0);

  int c0 = l & 15, kg = l >> 4, cx = l & 7;
  int ch0 = (kg ^ cx) * 8, ch1 = ((4 + kg) ^ cx) * 8;
  int ra = (w >> 2) * 64, rb = (w & 3) * 32;
  f32x4 zero = {0.f, 0.f, 0.f, 0.f};
  f32x4 acc[2][2][4][2];
#pragma unroll
  for (int a = 0; a < 2; ++a)
#pragma unroll
    for (int b = 0; b < 2; ++b)
#pragma unroll
      for (int m = 0; m < 4; ++m)
#pragma unroll
        for (int n = 0; n < 2; ++n) acc[a][b][m][n] = zero;

  for (int kt = 0; kt < NT; ++kt) {
    int db = kt & 1, dbn = db ^ 1;
    bool st = kt + 1 < NT;
    const short* Ab = S + db * 16384;
    const short* Bb = S + 32768 + db * 16384;
    short8 a1[4][2], a2[4][2], bF[2][2], bG[2][2];
    // ph0: (A0, Blo)
    PH_W4;
#pragma unroll
    for (int m = 0; m < 4; ++m) {
      a1[m][0] = *(const short8*)(Ab + (ra + m * 16 + c0) * 64 + ch0);
      a1[m][1] = *(const short8*)(Ab + (ra + m * 16 + c0) * 64 + ch1);
    }
#pragma unroll
    for (int n = 0; n < 2; ++n) {
      bF[n][0] = *(const short8*)(Bb + (rb + n * 16 + c0) * 64 + ch0);
      bF[n][1] = *(const short8*)(Bb + (rb + n * 16 + c0) * 64 + ch1);
    }
    if (st) SG_A0(kt + 1, dbn);
    PH_B;
    __builtin_amdgcn_s_setprio(1);
#pragma unroll
    for (int m = 0; m < 4; ++m)
#pragma unroll
      for (int n = 0; n < 2; ++n) {
        acc[0][0][m][n] = __builtin_amdgcn_mfma_f32_16x16x32_bf16(a1[m][0], bF[n][0], acc[0][0][m][n], 0, 0, 0);
        acc[0][0][m][n] = __builtin_amdgcn_mfma_f32_16x16x32_bf16(a1[m][1], bF[n][1], acc[0][0][m][n], 0, 0, 0);
      }
    __builtin_amdgcn_s_setprio(0);
    // ph1: (A0, Bhi)
    if (st) PH_W4; else PH_W2;
#pragma unroll
    for (int n = 0; n < 2; ++n) {
      bG[n][0] = *(const short8*)(Bb + 8192 + (rb + n * 16 + c0) * 64 + ch0);
      bG[n][1] = *(const short8*)(Bb + 8192 + (rb + n * 16 + c0) * 64 + ch1);
    }
    if (st) SG_B0(kt + 1, dbn);
    PH_B;
    __builtin_amdgcn_s_setprio(1);
#pragma unroll
    for (int m = 0; m < 4; ++m)
#pragma unroll
      for (int n = 0; n < 2; ++n) {
        acc[0][1][m][n] = __builtin_amdgcn_mfma_f32_16x16x32_bf16(a1[m][0], bG[n][0], acc[0][1][m][n], 0, 0, 0);
        acc[0][1][m][n] = __builtin_amdgcn_mfma_f32_16x16x32_bf16(a1[m][1], bG[n][1], acc[0][1][m][n], 0, 0, 0);
      }
    __builtin_amdgcn_s_setprio(0);
    // ph2: (A1, Bhi)
    if (st) PH_W4; else PH_W0;
#pragma unroll
    for (int m = 0; m < 4; ++m) {
      a2[m][0] = *(const short8*)(Ab + 8192 + (ra + m * 16 + c0) * 64 + ch0);
      a2[m][1] = *(const short8*)(Ab + 8192 + (ra + m * 16 + c0) * 64 + ch1);
    }
    if (st) SG_B1(kt + 1, dbn);
    PH_B;
    __builtin_amdgcn_s_setprio(1);
#pragma unroll
    for (int m = 0; m < 4; ++m)
#pragma unroll
      for (int n = 0; n < 2; ++n) {
        acc[1][1][m][n] = __builtin_amdgcn_mfma_f32_16x16x32_bf16(a2[m][0], bG[n][0], acc[1][1][m][n], 0, 0, 0);
        acc[1][1][m][n] = __builtin_amdgcn_mfma_f32_16x16x32_bf16(a2[m][1], bG[n][1], acc[1][1][m][n], 0, 0, 0);
      }
    __builtin_amdgcn_s_setprio(0);
    // ph3: (A1, Blo) — register-only
    if (st) SG_A1(kt + 1, dbn);
    __builtin_amdgcn_s_setprio(1);
#pragma unroll
    for (int m = 0; m < 4; ++m)
#pragma unroll
      for (int n = 0; n < 2; ++n) {
        acc[1][0][m][n] = __builtin_amdgcn_mfma_f32_16x16x32_bf16(a2[m][0], bF[n][0], acc[1][0][m][n], 0, 0, 0);
        acc[1][0][m][n] = __builtin_amdgcn_mfma_f32_16x16x32_bf16(a2[m][1], bF[n][1], acc[1][0][m][n], 0, 0, 0);
      }
    __builtin_amdgcn_s_setprio(0);
  }
#undef SG_A0
#undef SG_A1
#undef SG_B0
#undef SG_B1

  int r0 = (l >> 4) * 4;
#pragma unroll
  for (int a = 0; a < 2; ++a)
#pragma unroll
    for (int b = 0; b < 2; ++b)
#pragma unroll
      for (int m = 0; m < 4; ++m)
#pragma unroll
        for (int n = 0; n < 2; ++n)
#pragma unroll
          for (int r = 0; r < 4; ++r) {
            int row = mBase + a * 128 + ra + m * 16 + r0 + r;
            int col = nBase + b * 128 + rb + n * 16 + c0;
            part[(size_t)bz * (NTOK * DIM) + (size_t)row * DIM + col] = f2bf(acc[a][b][m][n][r]);
          }
}

__global__ __launch_bounds__(256) void k_red(const short* __restrict__ part,
                                             float* __restrict__ out) {
  int i = (blockIdx.x * 256 + threadIdx.x) * 8;
  float s[8] = {0.f, 0.f, 0.f, 0.f, 0.f, 0.f, 0.f, 0.f};
#pragma unroll
  for (int ks = 0; ks < 4; ++ks) {
    short8 v = *(const short8*)(part + (size_t)ks * (NTOK * DIM) + i);
#pragma unroll
    for (int jj = 0; jj < 8; ++jj) s[jj] += bf2f(v[jj]);
  }
  float4 lo = {s[0], s[1], s[2], s[3]};
  float4 hi = {s[4], s[5], s[6], s[7]};
  *(float4*)(out + i) = lo;
  *(float4*)(out + i + 4) = hi;
}

// ---------------- flash attention (unchanged) -------------------------------
__global__ __launch_bounds__(256) void k_attn(const short* __restrict__ qb,
                                              const short* __restrict__ kb,
                                              const short* __restrict__ vt,
                                              short* __restrict__ H) {
  __shared__ __align__(16) short Qs[64 * 64];
  __shared__ __align__(16) short Ks[128 * 64];
  __shared__ __align__(16) short Vs[64 * 128];
  __shared__ __align__(16) short Ps[4][16 * 128];
  int t = threadIdx.x, l = t & 63, w = t >> 6;
  int qt = blockIdx.x, bh = blockIdx.y;
  int b = bh >> 3, h = bh & 7;
  int q0 = qt * 64;

  int srow = w * 8 + (l >> 3);
  int schunk = (l & 7) ^ (l >> 3);
  {
    const short* Qg = qb + (size_t)(b * SEQ + q0 + srow) * AINNER + h * DH + schunk * 8;
    short* qs = Qs + w * 512 + l * 8;
#pragma unroll
    for (int i = 0; i < 2; ++i) g2l16(Qg + (size_t)(i * 32) * AINNER, qs + i * 2048);
  }
  const short* Kg = kb + (size_t)(b * SEQ + srow) * DH + schunk * 8;
  short* ksl = Ks + w * 512 + l * 8;
  int vrow = w * 4 + (l >> 4);
  int vchunk = (l & 15) ^ (vrow & 7);
  const short* Vg = vt + (size_t)b * DH * SEQ + (size_t)vrow * SEQ + vchunk * 8;
  short* vsl = Vs + w * 512 + l * 8;

#pragma unroll
  for (int i = 0; i < 4; ++i) {
    g2l16(Kg + (size_t)(i * 32) * DH, ksl + i * 2048);
    g2l16(Vg + (size_t)(i * 16) * SEQ, vsl + i * 2048);
  }

  float m_run[4], l_run[4];
  f32x4 zero = {0.f, 0.f, 0.f, 0.f};
  f32x4 Oacc[4];
#pragma unroll
  for (int r = 0; r < 4; ++r) { m_run[r] = -1e30f; l_run[r] = 0.f; }
#pragma unroll
  for (int n = 0; n < 4; ++n) Oacc[n] = zero;

  int c0 = l & 15, kg = l >> 4, cx = l & 7;
  short* pw = Ps[w];

  for (int kv0 = 0; kv0 < SEQ; kv0 += 128) {
    asm volatile("s_waitcnt vmcnt(0)\ns_barrier" ::: "memory");

    f32x4 sacc[8];
#pragma unroll
    for (int n = 0; n < 8; ++n) sacc[n] = zero;
#pragma unroll
    for (int kk = 0; kk < 2; ++kk) {
      int rr = w * 16 + c0;
      short8 aq = *(const short8*)(Qs + rr * 64 + ((kk * 4 + kg) ^ cx) * 8);
#pragma unroll
      for (int n = 0; n < 8; ++n) {
        int kr = n * 16 + c0;
        short8 bk = *(const short8*)(Ks + kr * 64 + ((kk * 4 + kg) ^ cx) * 8);
        sacc[n] = __builtin_amdgcn_mfma_f32_16x16x32_bf16(aq, bk, sacc[n], 0, 0, 0);
      }
    }
#pragma unroll
    for (int r = 0; r < 4; ++r) {
      float mx = -1e30f;
#pragma unroll
      for (int n = 0; n < 8; ++n) {
        sacc[n][r] *= 0.125f;
        mx = fmaxf(mx, sacc[n][r]);
      }
#pragma unroll
      for (int msk = 1; msk < 16; msk <<= 1) mx = fmaxf(mx, __shfl_xor(mx, msk));
      float nm = fmaxf(m_run[r], mx);
      float corr = __expf(m_run[r] - nm);
      m_run[r] = nm;
      float rs = 0.f;
#pragma unroll
      for (int n = 0; n < 8; ++n) {
        float p = __expf(sacc[n][r] - nm);
        sacc[n][r] = p;
        rs += p;
      }
#pragma unroll
      for (int msk = 1; msk < 16; msk <<= 1) rs += __shfl_xor(rs, msk);
      l_run[r] = l_run[r] * corr + rs;
      Oacc[0][r] *= corr; Oacc[1][r] *= corr; Oacc[2][r] *= corr; Oacc[3][r] *= corr;
    }
#pragma unroll
    for (int n = 0; n < 8; ++n)
#pragma unroll
      for (int r = 0; r < 4; ++r) {
        int pr = (l >> 4) * 4 + r;
        int pc = n * 16 + c0;
        pw[pr * 128 + ((pc >> 3) ^ (pr & 7)) * 8 + (pc & 7)] = f2bf(sacc[n][r]);
      }
    asm volatile("s_waitcnt lgkmcnt(0)" ::: "memory");
#pragma unroll
    for (int kk = 0; kk < 4; ++kk) {
      int pr = c0;
      short8 ap = *(const short8*)(pw + pr * 128 + ((kk * 4 + kg) ^ cx) * 8);
#pragma unroll
      for (int n = 0; n < 4; ++n) {
        int vr = n * 16 + c0;
        short8 bv = *(const short8*)(Vs + vr * 128 + ((kk * 4 + kg) ^ (vr & 7)) * 8);
        Oacc[n] = __builtin_amdgcn_mfma_f32_16x16x32_bf16(ap, bv, Oacc[n], 0, 0, 0);
      }
    }
    __syncthreads();
    int nx = kv0 + 128;
    if (nx < SEQ) {
#pragma unroll
      for (int i = 0; i < 4; ++i) {
        g2l16(Kg + (size_t)(nx + i * 32) * DH, ksl + i * 2048);
        g2l16(Vg + nx + (size_t)(i * 16) * SEQ, vsl + i * 2048);
      }
    }
  }
#pragma unroll
  for (int r = 0; r < 4; ++r) {
    float inv = 1.f / l_run[r];
    int row = b * SEQ + q0 + w * 16 + (l >> 4) * 4 + r;
#pragma unroll
    for (int n = 0; n < 4; ++n) {
      int col = h * DH + n * 16 + c0;
      H[(size_t)row * HCOLS + col] = f2bf(Oacc[n][r] * inv);
    }
  }
}

// ----------------------------------------------------------------------------
extern "C" void kernel_launch(void* const* d_in, const int* in_sizes, int n_in,
                              void* d_out, int out_size, void* d_ws, size_t ws_size,
                              hipStream_t stream) {
  const float* x     = (const float*)d_in[0];
  const float* gamma = (const float*)d_in[1];
  const float* w_f   = (const float*)d_in[2];
  const float* w_ao  = (const float*)d_in[3];
  const float* w_fo  = (const float*)d_in[4];
  float* out = (float*)d_out;

  char* ws = (char*)d_ws;
  size_t o = 0;
  short* WtF = (short*)(ws + o); o += (size_t)FUSED * DIM * 2;
  short* Wt2 = (short*)(ws + o); o += (size_t)DIM * HCOLS * 2;
  short* xn  = (short*)(ws + o); o += (size_t)NTOK * DIM * 2;
  short* qb  = (short*)(ws + o); o += (size_t)NTOK * AINNER * 2;
  short* kbf = (short*)(ws + o); o += (size_t)NTOK * DH * 2;
  short* vtb = (short*)(ws + o); o += (size_t)NTOK * DH * 2;
  short* H   = (short*)(ws + o); o += (size_t)NTOK * HCOLS * 2;
  short* part = (short*)(ws + o);

  k_transpose_wf<<<dim3(FUSED / 32, DIM / 32), 256, 0, stream>>>(w_f, WtF);
  k_transpose_w2<<<dim3(DIM / 32, HCOLS / 32), 256, 0, stream>>>(w_ao, w_fo, Wt2);
  k_ln<<<NTOK, 256, 0, stream>>>(x, gamma, xn);
  p1<<<dim3(37, 16), 512, 131072, stream>>>(xn, WtF, qb, kbf, vtb, H);
  k_attn<<<dim3(32, 16), 256, 0, stream>>>(qb, kbf, vtb, H);
  gemm_s<<<dim3(4, 16, 4), 512, 131072, stream>>>(H, Wt2, part);
  k_red<<<NTOK * DIM / 2048, 256, 0, stream>>>(part, out);
}